// Round 11
// baseline (133.836 us; speedup 1.0000x reference)
//
#include <hip/hip_runtime.h>

#define HEADS 4
#define OUT_CH 16
#define CCH 64            // HEADS*OUT_CH
#define IN_CH 128
#define NEG_SLOPE 0.2f
#define NXCD 8

typedef unsigned int       uint32;
typedef unsigned long long u64;
typedef unsigned short     u16;
typedef __attribute__((ext_vector_type(8))) short short8;
typedef __attribute__((ext_vector_type(4))) float f32x4;

__device__ __forceinline__ uint32 bf16_rne(float f) {
    uint32 u = __float_as_uint(f);
    return (u + 0x7fffu + ((u >> 16) & 1u)) >> 16;
}

// ---------------------------------------------------------------------------
// Zero kernel
// ---------------------------------------------------------------------------
__global__ void k_zero(int* __restrict__ p, int n) {
    int i = blockIdx.x * 256 + threadIdx.x;
    if (i < n) p[i] = 0;
}

// ---------------------------------------------------------------------------
// MFMA GEMM: h_bf[N][64] = bf16( f32(x[N][128]) @ w[128][64] ).  (R8, passing)
// ---------------------------------------------------------------------------
__global__ __launch_bounds__(256) void gat_gemm_mfma(const float* __restrict__ x,
                                                     const float* __restrict__ w,
                                                     u16* __restrict__ h_bf,
                                                     int N, int nwaves) {
    __shared__ u16 wT[64 * 136];   // 17.4 KB
    int t = threadIdx.x, lane = t & 63;

    for (int i = t; i < IN_CH * CCH; i += 256) {
        int k = i >> 6, c = i & 63;
        wT[c * 136 + k] = (u16)bf16_rne(w[i]);
    }
    __syncthreads();

    short8 bfrag[4][4];
    {
        int col = lane & 15, g = (lane >> 4) * 8;
        #pragma unroll
        for (int nt = 0; nt < 4; ++nt)
            #pragma unroll
            for (int kc = 0; kc < 4; ++kc)
                bfrag[nt][kc] = *(const short8*)&wT[(nt * 16 + col) * 136 + kc * 32 + g];
    }

    int gw = blockIdx.x * 4 + (t >> 6);
    int ntiles = (N + 15) >> 4;
    int row0 = lane & 15, kg = (lane >> 4) * 8;

    float4 cur[8], nxt[8];

    auto LOAD = [&](int tile, float4* buf) {
        int r = tile * 16 + row0;
        if (r >= N) r = N - 1;
        const float* xp = x + (size_t)r * IN_CH + kg;
        #pragma unroll
        for (int kc = 0; kc < 4; ++kc) {
            buf[kc * 2]     = *(const float4*)(xp + kc * 32);
            buf[kc * 2 + 1] = *(const float4*)(xp + kc * 32 + 4);
        }
    };

    int tile = gw;
    if (tile < ntiles) LOAD(tile, cur);
    for (; tile < ntiles; tile += nwaves) {
        int tn = tile + nwaves;
        if (tn < ntiles) LOAD(tn, nxt);

        short8 af[4];
        #pragma unroll
        for (int kc = 0; kc < 4; ++kc) {
            float4 u = cur[kc * 2], v = cur[kc * 2 + 1];
            short8 s;
            s[0] = (short)bf16_rne(u.x); s[1] = (short)bf16_rne(u.y);
            s[2] = (short)bf16_rne(u.z); s[3] = (short)bf16_rne(u.w);
            s[4] = (short)bf16_rne(v.x); s[5] = (short)bf16_rne(v.y);
            s[6] = (short)bf16_rne(v.z); s[7] = (short)bf16_rne(v.w);
            af[kc] = s;
        }

        f32x4 acc[4] = {{0.f,0.f,0.f,0.f},{0.f,0.f,0.f,0.f},
                        {0.f,0.f,0.f,0.f},{0.f,0.f,0.f,0.f}};
        #pragma unroll
        for (int kc = 0; kc < 4; ++kc)
            #pragma unroll
            for (int nt = 0; nt < 4; ++nt)
                acc[nt] = __builtin_amdgcn_mfma_f32_16x16x32_bf16(
                    af[kc], bfrag[nt][kc], acc[nt], 0, 0, 0);

        int rb = tile * 16;
        #pragma unroll
        for (int nt = 0; nt < 4; ++nt)
            #pragma unroll
            for (int r = 0; r < 4; ++r) {
                int row = rb + (lane >> 4) * 4 + r;
                if (row < N)
                    h_bf[(size_t)row * CCH + nt * 16 + (lane & 15)] =
                        (u16)bf16_rne(acc[nt][r]);
            }

        #pragma unroll
        for (int i = 0; i < 8; ++i) cur[i] = nxt[i];
    }
}

// ---------------------------------------------------------------------------
// Per-(row,head) attention dots from h_bf (unchanged)
// ---------------------------------------------------------------------------
__global__ __launch_bounds__(256) void k_dots(const u16* __restrict__ h_bf,
                                              const float* __restrict__ att,
                                              float* __restrict__ d_i,
                                              float* __restrict__ d_j, int N) {
    int idx = blockIdx.x * 256 + threadIdx.x;
    if (idx >= N * HEADS) return;
    int head = idx & 3;
    const u16* hp = h_bf + (size_t)(idx >> 2) * CCH + head * OUT_CH;
    const float* ap = att + head * (2 * OUT_CH);

    uint4 q0 = *(const uint4*)hp;
    uint4 q1 = *(const uint4*)(hp + 8);
    uint32 words[8] = {q0.x, q0.y, q0.z, q0.w, q1.x, q1.y, q1.z, q1.w};
    float si = 0.f, sj = 0.f;
    #pragma unroll
    for (int i = 0; i < 8; ++i) {
        float lo = __uint_as_float(words[i] << 16);
        float hi = __uint_as_float(words[i] & 0xffff0000u);
        si = fmaf(lo, ap[i * 2], si);      si = fmaf(hi, ap[i * 2 + 1], si);
        sj = fmaf(lo, ap[16 + i * 2], sj); sj = fmaf(hi, ap[16 + i * 2 + 1], sj);
    }
    d_i[idx] = si;
    d_j[idx] = sj;
}

// ---------------------------------------------------------------------------
// XCD-partitioned histogram: block b = (slice b>>3, part b&7). The 8 blocks
// of a slice read the same coalesced edge chunk; each acts only on dests in
// its 1/8 node range -> deg atomics stay XCD-local (perf heuristic only).
// ---------------------------------------------------------------------------
__global__ __launch_bounds__(256) void k_count(const int* __restrict__ cols,
                                               int* __restrict__ deg,
                                               int E, int N, int slice_len) {
    int part = blockIdx.x & (NXCD - 1);
    int slice = blockIdx.x >> 3;
    int tot = E + N;
    int start = slice * slice_len;
    int end = min(start + slice_len, tot);
    int lo = part * N / NXCD, hi = (part + 1) * N / NXCD;

    for (int e = start + threadIdx.x; e < end; e += 256) {
        int c = (e < E) ? cols[e] : (e - E);
        if (c >= lo && c < hi) atomicAdd(&deg[c], 1);
    }
}

// ---------------------------------------------------------------------------
// Scan: block-local -> partials -> add (emits cur = offs copy)
// ---------------------------------------------------------------------------
__global__ __launch_bounds__(256) void k_scan_blk(const int* __restrict__ deg,
                                                  int* __restrict__ offs,
                                                  int* __restrict__ partials, int N) {
    __shared__ int wsum[4];
    int t = threadIdx.x, lane = t & 63, wid = t >> 6;
    int base = blockIdx.x * 1024 + t * 4;
    int v0 = 0, v1 = 0, v2 = 0, v3 = 0;
    if (base + 3 < N) {
        int4 q = *(const int4*)(deg + base);
        v0 = q.x; v1 = q.y; v2 = q.z; v3 = q.w;
    } else {
        if (base     < N) v0 = deg[base];
        if (base + 1 < N) v1 = deg[base + 1];
        if (base + 2 < N) v2 = deg[base + 2];
        if (base + 3 < N) v3 = deg[base + 3];
    }
    int ts = v0 + v1 + v2 + v3;
    int sc = ts;
    #pragma unroll
    for (int off = 1; off < 64; off <<= 1) {
        int u = __shfl_up(sc, off);
        if (lane >= off) sc += u;
    }
    if (lane == 63) wsum[wid] = sc;
    __syncthreads();
    int wb = 0;
    for (int i = 0; i < wid; ++i) wb += wsum[i];
    int excl = wb + sc - ts;
    if (base     < N) offs[base]     = excl;
    if (base + 1 < N) offs[base + 1] = excl + v0;
    if (base + 2 < N) offs[base + 2] = excl + v0 + v1;
    if (base + 3 < N) offs[base + 3] = excl + v0 + v1 + v2;
    if (t == 255) partials[blockIdx.x] = wb + sc;
}

__global__ __launch_bounds__(64) void k_scan_part(int* __restrict__ partials, int NB) {
    int lane = threadIdx.x;
    int carry = 0;
    for (int b = 0; b < NB; b += 64) {
        int idx = b + lane;
        int v = (idx < NB) ? partials[idx] : 0;
        int sc = v;
        #pragma unroll
        for (int off = 1; off < 64; off <<= 1) {
            int u = __shfl_up(sc, off);
            if (lane >= off) sc += u;
        }
        if (idx < NB) partials[idx] = carry + sc - v;
        carry += __shfl(sc, 63);
    }
    if (lane == 0) partials[NB] = carry;
}

__global__ void k_scan_add(int* __restrict__ offs, int* __restrict__ cur,
                           const int* __restrict__ partials, int N, int NB) {
    int i = blockIdx.x * 256 + threadIdx.x;
    if (i < N) {
        int v = offs[i] + partials[i >> 10];
        offs[i] = v;
        cur[i] = v;
    }
    if (i == 0) offs[N] = partials[NB];
}

// ---------------------------------------------------------------------------
// XCD-partitioned scatter + alpha: pos = cur[c]++ (XCD-local atomic).
// Record = 8 B: row (17b) + 4x 11-bit fixed-point alpha.
// ---------------------------------------------------------------------------
__global__ __launch_bounds__(256) void k_scatter_alpha(const int* __restrict__ rows,
                                                       const int* __restrict__ cols,
                                                       int* __restrict__ cur,
                                                       const float* __restrict__ d_i,
                                                       const float* __restrict__ d_j,
                                                       u64* __restrict__ srec,
                                                       int E, int N, int slice_len) {
    int part = blockIdx.x & (NXCD - 1);
    int slice = blockIdx.x >> 3;
    int tot = E + N;
    int start = slice * slice_len;
    int end = min(start + slice_len, tot);
    int lo = part * N / NXCD, hi = (part + 1) * N / NXCD;

    for (int e = start + threadIdx.x; e < end; e += 256) {
        int c = (e < E) ? cols[e] : (e - E);
        if (c < lo || c >= hi) continue;
        int r = (e < E) ? rows[e] : c;

        int pos = atomicAdd(&cur[c], 1);

        float4 di4 = *(const float4*)(d_i + (size_t)r * HEADS);
        float4 dj4 = *(const float4*)(d_j + (size_t)c * HEADS);
        float l0 = di4.x + dj4.x, l1 = di4.y + dj4.y;
        float l2 = di4.z + dj4.z, l3 = di4.w + dj4.w;
        l0 = l0 > 0.f ? l0 : NEG_SLOPE * l0;
        l1 = l1 > 0.f ? l1 : NEG_SLOPE * l1;
        l2 = l2 > 0.f ? l2 : NEG_SLOPE * l2;
        l3 = l3 > 0.f ? l3 : NEG_SLOPE * l3;
        float m = fmaxf(fmaxf(l0, l1), fmaxf(l2, l3));
        float e0 = __expf(l0 - m), e1 = __expf(l1 - m);
        float e2 = __expf(l2 - m), e3 = __expf(l3 - m);
        float inv = 1.f / (e0 + e1 + e2 + e3);

        uint32 q0 = (uint32)(e0 * inv * 2047.f + 0.5f);
        uint32 q1 = (uint32)(e1 * inv * 2047.f + 0.5f);
        uint32 q2 = (uint32)(e2 * inv * 2047.f + 0.5f);
        uint32 q3 = (uint32)(e3 * inv * 2047.f + 0.5f);

        u64 rec = (u64)(uint32)r
                | ((u64)q0 << 17) | ((u64)q1 << 28)
                | ((u64)q2 << 39) | ((u64)q3 << 50);
        srec[pos] = rec;
    }
}

// ---------------------------------------------------------------------------
// Accumulate: 4 dests per wave (16 lanes each, 4 channels/lane). (R10, passing)
// ---------------------------------------------------------------------------
__global__ __launch_bounds__(256) void k_accum(const int* __restrict__ offs,
                                               const u64* __restrict__ srec,
                                               const u16* __restrict__ h_bf,
                                               const float* __restrict__ bias,
                                               float* __restrict__ out, int N) {
    int t = threadIdx.x;
    int wid = t >> 6, lane = t & 63;
    int g = lane >> 4, sub = lane & 15;
    int node = blockIdx.x * 16 + wid * 4 + g;
    int c = (node < N) ? node : N - 1;

    int s = offs[c], e = offs[c + 1];
    int deg = e - s;                       // >= 1 (self-loops)
    int md = deg;
    md = max(md, __shfl_xor(md, 16));
    md = max(md, __shfl_xor(md, 32));      // max over the wave's 4 groups

    int shift = 17 + 11 * (sub >> 2);      // this lane's head field
    float a0 = 0.f, a1 = 0.f, a2 = 0.f, a3 = 0.f;

    #pragma unroll 2
    for (int r = 0; r < md; ++r) {
        int idx = s + ((r < deg) ? r : (deg - 1));
        u64 rec = srec[idx];
        int row = (int)((uint32)rec & 0x1FFFFu);
        float a = (float)((uint32)(rec >> shift) & 0x7FFu) * (1.f / 2047.f);
        if (r >= deg) a = 0.f;
        uint2 hb = *(const uint2*)(h_bf + (size_t)row * CCH + sub * 4);
        a0 = fmaf(__uint_as_float(hb.x << 16),         a, a0);
        a1 = fmaf(__uint_as_float(hb.x & 0xffff0000u), a, a1);
        a2 = fmaf(__uint_as_float(hb.y << 16),         a, a2);
        a3 = fmaf(__uint_as_float(hb.y & 0xffff0000u), a, a3);
    }

    if (node < N) {
        float4 b = *(const float4*)(bias + sub * 4);
        float4 o = {a0 + b.x, a1 + b.y, a2 + b.z, a3 + b.w};
        *(float4*)(out + (size_t)node * CCH + sub * 4) = o;
    }
}

extern "C" void kernel_launch(void* const* d_in, const int* in_sizes, int n_in,
                              void* d_out, int out_size, void* d_ws, size_t ws_size,
                              hipStream_t stream) {
    const float* x    = (const float*)d_in[0];
    const int*   ei   = (const int*)  d_in[1];
    const float* w    = (const float*)d_in[2];
    const float* att  = (const float*)d_in[3];
    const float* bias = (const float*)d_in[4];
    float* out = (float*)d_out;

    int N = in_sizes[0] / IN_CH;
    int E = in_sizes[1] / 2;
    const int* rows = ei;
    const int* cols = ei + E;
    int total_e = E + N;
    int NB = (N + 1023) / 1024;
    int Npad = (N + 3) & ~3;

    char* ws = (char*)d_ws;
    auto carve = [&](size_t bytes) {
        char* p = ws;
        ws += (bytes + 255) & ~(size_t)255;
        return p;
    };
    u16*   h_bf   = (u16*)  carve((size_t)N * CCH * 2);          // 6.4 MB
    float* di     = (float*)carve((size_t)N * HEADS * 4);        // 0.8 MB
    float* dj     = (float*)carve((size_t)N * HEADS * 4);        // 0.8 MB
    int*   deg    = (int*)  carve((size_t)Npad * 4);
    int*   offs   = (int*)  carve((size_t)(N + 1) * 4);
    int*   cur    = (int*)  carve((size_t)N * 4);
    int*   parts  = (int*)  carve((size_t)(NB + 1) * 4);
    u64*   srec   = (u64*)  carve((size_t)total_e * 8);          // 6.8 MB

    const int GEMM_BLOCKS = 768;                 // 3072 waves
    const int GEMM_WAVES  = GEMM_BLOCKS * 4;
    const int NSLICE = 256;                      // edge slices
    const int EGRID  = NSLICE * NXCD;            // 2048 blocks
    int slice_len = (total_e + NSLICE - 1) / NSLICE;

    k_zero<<<(Npad + 255) / 256, 256, 0, stream>>>(deg, Npad);
    k_count<<<EGRID, 256, 0, stream>>>(cols, deg, E, N, slice_len);
    k_scan_blk<<<NB, 256, 0, stream>>>(deg, offs, parts, N);
    k_scan_part<<<1, 64, 0, stream>>>(parts, NB);
    k_scan_add<<<(N + 255) / 256, 256, 0, stream>>>(offs, cur, parts, N, NB);
    gat_gemm_mfma<<<GEMM_BLOCKS, 256, 0, stream>>>(x, w, h_bf, N, GEMM_WAVES);
    k_dots<<<(N * HEADS + 255) / 256, 256, 0, stream>>>(h_bf, att, di, dj, N);
    k_scatter_alpha<<<EGRID, 256, 0, stream>>>(rows, cols, cur, di, dj, srec,
                                               E, N, slice_len);
    k_accum<<<(N + 15) / 16, 256, 0, stream>>>(offs, srec, h_bf, bias, out, N);
}

// Round 12
// 111.429 us; speedup vs baseline: 1.2011x; 1.2011x over previous
//
#include <hip/hip_runtime.h>

#define HEADS 4
#define OUT_CH 16
#define CCH 64            // HEADS*OUT_CH
#define IN_CH 128
#define NEG_SLOPE 0.2f

typedef unsigned int       uint32;
typedef unsigned long long u64;
typedef unsigned short     u16;
typedef __attribute__((ext_vector_type(8))) short short8;
typedef __attribute__((ext_vector_type(4))) float f32x4;

__device__ __forceinline__ uint32 bf16_rne(float f) {
    uint32 u = __float_as_uint(f);
    return (u + 0x7fffu + ((u >> 16) & 1u)) >> 16;
}

// ---------------------------------------------------------------------------
// Zero kernel
// ---------------------------------------------------------------------------
__global__ void k_zero(int* __restrict__ p, int n) {
    int i = blockIdx.x * 256 + threadIdx.x;
    if (i < n) p[i] = 0;
}

// ---------------------------------------------------------------------------
// MFMA GEMM: h_bf[N][64] = bf16( f32(x[N][128]) @ w[128][64] ).  (R8, passing)
// Grid sized so each wave gets exactly one 16-row tile (no tail round).
// ---------------------------------------------------------------------------
__global__ __launch_bounds__(256) void gat_gemm_mfma(const float* __restrict__ x,
                                                     const float* __restrict__ w,
                                                     u16* __restrict__ h_bf,
                                                     int N, int nwaves) {
    __shared__ u16 wT[64 * 136];   // 17.4 KB
    int t = threadIdx.x, lane = t & 63;

    for (int i = t; i < IN_CH * CCH; i += 256) {
        int k = i >> 6, c = i & 63;
        wT[c * 136 + k] = (u16)bf16_rne(w[i]);
    }
    __syncthreads();

    short8 bfrag[4][4];
    {
        int col = lane & 15, g = (lane >> 4) * 8;
        #pragma unroll
        for (int nt = 0; nt < 4; ++nt)
            #pragma unroll
            for (int kc = 0; kc < 4; ++kc)
                bfrag[nt][kc] = *(const short8*)&wT[(nt * 16 + col) * 136 + kc * 32 + g];
    }

    int gw = blockIdx.x * 4 + (t >> 6);
    int ntiles = (N + 15) >> 4;
    int row0 = lane & 15, kg = (lane >> 4) * 8;

    float4 cur[8], nxt[8];

    auto LOAD = [&](int tile, float4* buf) {
        int r = tile * 16 + row0;
        if (r >= N) r = N - 1;
        const float* xp = x + (size_t)r * IN_CH + kg;
        #pragma unroll
        for (int kc = 0; kc < 4; ++kc) {
            buf[kc * 2]     = *(const float4*)(xp + kc * 32);
            buf[kc * 2 + 1] = *(const float4*)(xp + kc * 32 + 4);
        }
    };

    int tile = gw;
    if (tile < ntiles) LOAD(tile, cur);
    for (; tile < ntiles; tile += nwaves) {
        int tn = tile + nwaves;
        if (tn < ntiles) LOAD(tn, nxt);

        short8 af[4];
        #pragma unroll
        for (int kc = 0; kc < 4; ++kc) {
            float4 u = cur[kc * 2], v = cur[kc * 2 + 1];
            short8 s;
            s[0] = (short)bf16_rne(u.x); s[1] = (short)bf16_rne(u.y);
            s[2] = (short)bf16_rne(u.z); s[3] = (short)bf16_rne(u.w);
            s[4] = (short)bf16_rne(v.x); s[5] = (short)bf16_rne(v.y);
            s[6] = (short)bf16_rne(v.z); s[7] = (short)bf16_rne(v.w);
            af[kc] = s;
        }

        f32x4 acc[4] = {{0.f,0.f,0.f,0.f},{0.f,0.f,0.f,0.f},
                        {0.f,0.f,0.f,0.f},{0.f,0.f,0.f,0.f}};
        #pragma unroll
        for (int kc = 0; kc < 4; ++kc)
            #pragma unroll
            for (int nt = 0; nt < 4; ++nt)
                acc[nt] = __builtin_amdgcn_mfma_f32_16x16x32_bf16(
                    af[kc], bfrag[nt][kc], acc[nt], 0, 0, 0);

        int rb = tile * 16;
        #pragma unroll
        for (int nt = 0; nt < 4; ++nt)
            #pragma unroll
            for (int r = 0; r < 4; ++r) {
                int row = rb + (lane >> 4) * 4 + r;
                if (row < N)
                    h_bf[(size_t)row * CCH + nt * 16 + (lane & 15)] =
                        (u16)bf16_rne(acc[nt][r]);
            }

        #pragma unroll
        for (int i = 0; i < 8; ++i) cur[i] = nxt[i];
    }
}

// ---------------------------------------------------------------------------
// Per-(row,head) attention dots from h_bf (unchanged)
// ---------------------------------------------------------------------------
__global__ __launch_bounds__(256) void k_dots(const u16* __restrict__ h_bf,
                                              const float* __restrict__ att,
                                              float* __restrict__ d_i,
                                              float* __restrict__ d_j, int N) {
    int idx = blockIdx.x * 256 + threadIdx.x;
    if (idx >= N * HEADS) return;
    int head = idx & 3;
    const u16* hp = h_bf + (size_t)(idx >> 2) * CCH + head * OUT_CH;
    const float* ap = att + head * (2 * OUT_CH);

    uint4 q0 = *(const uint4*)hp;
    uint4 q1 = *(const uint4*)(hp + 8);
    uint32 words[8] = {q0.x, q0.y, q0.z, q0.w, q1.x, q1.y, q1.z, q1.w};
    float si = 0.f, sj = 0.f;
    #pragma unroll
    for (int i = 0; i < 8; ++i) {
        float lo = __uint_as_float(words[i] << 16);
        float hi = __uint_as_float(words[i] & 0xffff0000u);
        si = fmaf(lo, ap[i * 2], si);      si = fmaf(hi, ap[i * 2 + 1], si);
        sj = fmaf(lo, ap[16 + i * 2], sj); sj = fmaf(hi, ap[16 + i * 2 + 1], sj);
    }
    d_i[idx] = si;
    d_j[idx] = sj;
}

// ---------------------------------------------------------------------------
// Count + rank: 4 edges/thread, int4 cols load + int4 rank store ->
// 4 independent atomic chains in flight per thread (atomic-latency bound).
// ---------------------------------------------------------------------------
__global__ __launch_bounds__(256) void k_count_rank(const int* __restrict__ cols,
                                                    int* __restrict__ deg,
                                                    int* __restrict__ rank,
                                                    int E, int N) {
    int tot = E + N;
    int i = (blockIdx.x * 256 + threadIdx.x) * 4;
    if (i + 3 < tot) {
        int4 cc;
        if (i + 3 < E) {
            cc = *(const int4*)(cols + i);
        } else {
            cc.x = (i     < E) ? cols[i]     : i - E;
            cc.y = (i + 1 < E) ? cols[i + 1] : i + 1 - E;
            cc.z = (i + 2 < E) ? cols[i + 2] : i + 2 - E;
            cc.w = (i + 3 < E) ? cols[i + 3] : i + 3 - E;
        }
        int r0 = atomicAdd(&deg[cc.x], 1);
        int r1 = atomicAdd(&deg[cc.y], 1);
        int r2 = atomicAdd(&deg[cc.z], 1);
        int r3 = atomicAdd(&deg[cc.w], 1);
        *(int4*)(rank + i) = make_int4(r0, r1, r2, r3);
    } else {
        for (int e = i; e < tot; ++e) {
            int c = (e < E) ? cols[e] : (e - E);
            rank[e] = atomicAdd(&deg[c], 1);
        }
    }
}

// ---------------------------------------------------------------------------
// Scan: block-local -> add (partial prefix computed inline; scan_part removed)
// ---------------------------------------------------------------------------
__global__ __launch_bounds__(256) void k_scan_blk(const int* __restrict__ deg,
                                                  int* __restrict__ offs,
                                                  int* __restrict__ partials, int N) {
    __shared__ int wsum[4];
    int t = threadIdx.x, lane = t & 63, wid = t >> 6;
    int base = blockIdx.x * 1024 + t * 4;
    int v0 = 0, v1 = 0, v2 = 0, v3 = 0;
    if (base + 3 < N) {
        int4 q = *(const int4*)(deg + base);
        v0 = q.x; v1 = q.y; v2 = q.z; v3 = q.w;
    } else {
        if (base     < N) v0 = deg[base];
        if (base + 1 < N) v1 = deg[base + 1];
        if (base + 2 < N) v2 = deg[base + 2];
        if (base + 3 < N) v3 = deg[base + 3];
    }
    int ts = v0 + v1 + v2 + v3;
    int sc = ts;
    #pragma unroll
    for (int off = 1; off < 64; off <<= 1) {
        int u = __shfl_up(sc, off);
        if (lane >= off) sc += u;
    }
    if (lane == 63) wsum[wid] = sc;
    __syncthreads();
    int wb = 0;
    for (int i = 0; i < wid; ++i) wb += wsum[i];
    int excl = wb + sc - ts;
    if (base     < N) offs[base]     = excl;
    if (base + 1 < N) offs[base + 1] = excl + v0;
    if (base + 2 < N) offs[base + 2] = excl + v0 + v1;
    if (base + 3 < N) offs[base + 3] = excl + v0 + v1 + v2;
    if (t == 255) partials[blockIdx.x] = wb + sc;
}

// each 256-thread block covers i in [256b, 256b+256) -> single partial p=b>>2
__global__ void k_scan_add(int* __restrict__ offs,
                           const int* __restrict__ partials, int N, int NB) {
    int b = blockIdx.x;
    int p = b >> 2;
    int base = 0;
    for (int j = 0; j < p; ++j) base += partials[j];   // wave-uniform scalar loop
    int i = b * 256 + threadIdx.x;
    if (i < N) offs[i] += base;
    if (i == 0) {
        int tot = 0;
        for (int j = 0; j < NB; ++j) tot += partials[j];
        offs[N] = tot;
    }
}

// ---------------------------------------------------------------------------
// Scatter + alpha: pos = offs[c] + rank[e]. Record = 8 B:
//   bits [0,17): row; bits [17+11h, ...): alpha[h] as 11-bit fixed point.
// ---------------------------------------------------------------------------
__global__ __launch_bounds__(256) void k_scatter_alpha(const int* __restrict__ rows,
                                                       const int* __restrict__ cols,
                                                       const int* __restrict__ offs,
                                                       const int* __restrict__ rank,
                                                       const float* __restrict__ d_i,
                                                       const float* __restrict__ d_j,
                                                       u64* __restrict__ srec,
                                                       int E, int N) {
    int e = blockIdx.x * blockDim.x + threadIdx.x;
    if (e >= E + N) return;
    int r, c;
    if (e < E) { r = rows[e]; c = cols[e]; }
    else       { r = e - E;   c = r; }
    int pos = offs[c] + rank[e];

    float4 di4 = *(const float4*)(d_i + (size_t)r * HEADS);
    float4 dj4 = *(const float4*)(d_j + (size_t)c * HEADS);
    float l0 = di4.x + dj4.x, l1 = di4.y + dj4.y;
    float l2 = di4.z + dj4.z, l3 = di4.w + dj4.w;
    l0 = l0 > 0.f ? l0 : NEG_SLOPE * l0;
    l1 = l1 > 0.f ? l1 : NEG_SLOPE * l1;
    l2 = l2 > 0.f ? l2 : NEG_SLOPE * l2;
    l3 = l3 > 0.f ? l3 : NEG_SLOPE * l3;
    float m = fmaxf(fmaxf(l0, l1), fmaxf(l2, l3));
    float e0 = __expf(l0 - m), e1 = __expf(l1 - m);
    float e2 = __expf(l2 - m), e3 = __expf(l3 - m);
    float inv = 1.f / (e0 + e1 + e2 + e3);

    uint32 q0 = (uint32)(e0 * inv * 2047.f + 0.5f);
    uint32 q1 = (uint32)(e1 * inv * 2047.f + 0.5f);
    uint32 q2 = (uint32)(e2 * inv * 2047.f + 0.5f);
    uint32 q3 = (uint32)(e3 * inv * 2047.f + 0.5f);

    u64 rec = (u64)(uint32)r
            | ((u64)q0 << 17) | ((u64)q1 << 28)
            | ((u64)q2 << 39) | ((u64)q3 << 50);
    srec[pos] = rec;
}

// ---------------------------------------------------------------------------
// Accumulate: 4 dests per wave (16 lanes each, 4 channels/lane), unroll 4.
// ---------------------------------------------------------------------------
__global__ __launch_bounds__(256) void k_accum(const int* __restrict__ offs,
                                               const u64* __restrict__ srec,
                                               const u16* __restrict__ h_bf,
                                               const float* __restrict__ bias,
                                               float* __restrict__ out, int N) {
    int t = threadIdx.x;
    int wid = t >> 6, lane = t & 63;
    int g = lane >> 4, sub = lane & 15;
    int node = blockIdx.x * 16 + wid * 4 + g;
    int c = (node < N) ? node : N - 1;

    int s = offs[c], e = offs[c + 1];
    int deg = e - s;                       // >= 1 (self-loops)
    int md = deg;
    md = max(md, __shfl_xor(md, 16));
    md = max(md, __shfl_xor(md, 32));      // max over the wave's 4 groups

    int shift = 17 + 11 * (sub >> 2);      // this lane's head field
    float a0 = 0.f, a1 = 0.f, a2 = 0.f, a3 = 0.f;

    #pragma unroll 4
    for (int r = 0; r < md; ++r) {
        int idx = s + ((r < deg) ? r : (deg - 1));
        u64 rec = srec[idx];
        int row = (int)((uint32)rec & 0x1FFFFu);
        float a = (float)((uint32)(rec >> shift) & 0x7FFu) * (1.f / 2047.f);
        if (r >= deg) a = 0.f;
        uint2 hb = *(const uint2*)(h_bf + (size_t)row * CCH + sub * 4);
        a0 = fmaf(__uint_as_float(hb.x << 16),         a, a0);
        a1 = fmaf(__uint_as_float(hb.x & 0xffff0000u), a, a1);
        a2 = fmaf(__uint_as_float(hb.y << 16),         a, a2);
        a3 = fmaf(__uint_as_float(hb.y & 0xffff0000u), a, a3);
    }

    if (node < N) {
        float4 b = *(const float4*)(bias + sub * 4);
        float4 o = {a0 + b.x, a1 + b.y, a2 + b.z, a3 + b.w};
        *(float4*)(out + (size_t)node * CCH + sub * 4) = o;
    }
}

extern "C" void kernel_launch(void* const* d_in, const int* in_sizes, int n_in,
                              void* d_out, int out_size, void* d_ws, size_t ws_size,
                              hipStream_t stream) {
    const float* x    = (const float*)d_in[0];
    const int*   ei   = (const int*)  d_in[1];
    const float* w    = (const float*)d_in[2];
    const float* att  = (const float*)d_in[3];
    const float* bias = (const float*)d_in[4];
    float* out = (float*)d_out;

    int N = in_sizes[0] / IN_CH;
    int E = in_sizes[1] / 2;
    const int* rows = ei;
    const int* cols = ei + E;
    int total_e = E + N;
    int NB = (N + 1023) / 1024;
    int Npad = (N + 3) & ~3;

    char* ws = (char*)d_ws;
    auto carve = [&](size_t bytes) {
        char* p = ws;
        ws += (bytes + 255) & ~(size_t)255;
        return p;
    };
    u16*   h_bf   = (u16*)  carve((size_t)N * CCH * 2);          // 6.4 MB
    float* di     = (float*)carve((size_t)N * HEADS * 4);        // 0.8 MB
    float* dj     = (float*)carve((size_t)N * HEADS * 4);        // 0.8 MB
    int*   deg    = (int*)  carve((size_t)Npad * 4);
    int*   offs   = (int*)  carve((size_t)(N + 1) * 4);
    int*   parts  = (int*)  carve((size_t)(NB + 1) * 4);
    int*   rank   = (int*)  carve((size_t)total_e * 4);          // 3.4 MB
    u64*   srec   = (u64*)  carve((size_t)total_e * 8);          // 6.8 MB

    int ntiles = (N + 15) >> 4;
    int gemm_blocks = (ntiles + 3) / 4;          // 1 tile per wave
    if (gemm_blocks > 2048) gemm_blocks = 2048;
    int gemm_waves = gemm_blocks * 4;

    k_zero<<<(Npad + 255) / 256, 256, 0, stream>>>(deg, Npad);
    k_count_rank<<<((total_e + 3) / 4 + 255) / 256, 256, 0, stream>>>(cols, deg, rank, E, N);
    k_scan_blk<<<NB, 256, 0, stream>>>(deg, offs, parts, N);
    k_scan_add<<<(N + 255) / 256, 256, 0, stream>>>(offs, parts, N, NB);
    gat_gemm_mfma<<<gemm_blocks, 256, 0, stream>>>(x, w, h_bf, N, gemm_waves);
    k_dots<<<(N * HEADS + 255) / 256, 256, 0, stream>>>(h_bf, att, di, dj, N);
    k_scatter_alpha<<<(total_e + 255) / 256, 256, 0, stream>>>(rows, cols, offs, rank,
                                                               di, dj, srec, E, N);
    k_accum<<<(N + 15) / 16, 256, 0, stream>>>(offs, srec, h_bf, bias, out, N);
}

// Round 13
// 108.098 us; speedup vs baseline: 1.2381x; 1.0308x over previous
//
#include <hip/hip_runtime.h>

#define HEADS 4
#define OUT_CH 16
#define CCH 64            // HEADS*OUT_CH
#define IN_CH 128
#define NEG_SLOPE 0.2f

typedef unsigned int       uint32;
typedef unsigned long long u64;
typedef unsigned short     u16;
typedef __attribute__((ext_vector_type(8))) short short8;
typedef __attribute__((ext_vector_type(4))) float f32x4;

__device__ __forceinline__ uint32 bf16_rne(float f) {
    uint32 u = __float_as_uint(f);
    return (u + 0x7fffu + ((u >> 16) & 1u)) >> 16;
}

// ---------------------------------------------------------------------------
// Zero kernel
// ---------------------------------------------------------------------------
__global__ void k_zero(int* __restrict__ p, int n) {
    int i = blockIdx.x * 256 + threadIdx.x;
    if (i < n) p[i] = 0;
}

// ---------------------------------------------------------------------------
// FAT kernel: blocks [0, GB) = MFMA GEMM + fused d_i/d_j dot epilogue;
//             blocks [GB, ..) = count_rank (4 atomic chains/thread).
// The two paths are independent; count's atomic latency hides under the
// fetch-bound GEMM. Branch is block-uniform (syncthreads only in gemm path).
// ---------------------------------------------------------------------------
__global__ __launch_bounds__(256) void k_fat(const float* __restrict__ x,
                                             const float* __restrict__ w,
                                             const float* __restrict__ att,
                                             u16* __restrict__ h_bf,
                                             float* __restrict__ d_i,
                                             float* __restrict__ d_j,
                                             const int* __restrict__ cols,
                                             int* __restrict__ deg,
                                             int* __restrict__ rank,
                                             int N, int E, int GB, int nwaves) {
    int t = threadIdx.x;

    if ((int)blockIdx.x < GB) {
        // ---------------- GEMM path ----------------
        __shared__ u16 wT[64 * 136];   // 17.4 KB
        int lane = t & 63;

        for (int i = t; i < IN_CH * CCH; i += 256) {
            int k = i >> 6, c = i & 63;
            wT[c * 136 + k] = (u16)bf16_rne(w[i]);
        }
        __syncthreads();

        short8 bfrag[4][4];
        int col = lane & 15;
        {
            int g = (lane >> 4) * 8;
            #pragma unroll
            for (int nt = 0; nt < 4; ++nt)
                #pragma unroll
                for (int kc = 0; kc < 4; ++kc)
                    bfrag[nt][kc] = *(const short8*)&wT[(nt * 16 + col) * 136 + kc * 32 + g];
        }

        // preload attention vectors for this lane's column
        float ai_c[4], aj_c[4];
        #pragma unroll
        for (int nt = 0; nt < 4; ++nt) {
            ai_c[nt] = att[nt * (2 * OUT_CH) + col];
            aj_c[nt] = att[nt * (2 * OUT_CH) + OUT_CH + col];
        }

        int gw = blockIdx.x * 4 + (t >> 6);
        int ntiles = (N + 15) >> 4;
        int row0 = lane & 15, kg = (lane >> 4) * 8;

        float4 cur[8], nxt[8];

        auto LOAD = [&](int tile, float4* buf) {
            int r = tile * 16 + row0;
            if (r >= N) r = N - 1;
            const float* xp = x + (size_t)r * IN_CH + kg;
            #pragma unroll
            for (int kc = 0; kc < 4; ++kc) {
                buf[kc * 2]     = *(const float4*)(xp + kc * 32);
                buf[kc * 2 + 1] = *(const float4*)(xp + kc * 32 + 4);
            }
        };

        int tile = gw;
        if (tile < ntiles) LOAD(tile, cur);
        for (; tile < ntiles; tile += nwaves) {
            int tn = tile + nwaves;
            if (tn < ntiles) LOAD(tn, nxt);

            short8 af[4];
            #pragma unroll
            for (int kc = 0; kc < 4; ++kc) {
                float4 u = cur[kc * 2], v = cur[kc * 2 + 1];
                short8 s;
                s[0] = (short)bf16_rne(u.x); s[1] = (short)bf16_rne(u.y);
                s[2] = (short)bf16_rne(u.z); s[3] = (short)bf16_rne(u.w);
                s[4] = (short)bf16_rne(v.x); s[5] = (short)bf16_rne(v.y);
                s[6] = (short)bf16_rne(v.z); s[7] = (short)bf16_rne(v.w);
                af[kc] = s;
            }

            f32x4 acc[4] = {{0.f,0.f,0.f,0.f},{0.f,0.f,0.f,0.f},
                            {0.f,0.f,0.f,0.f},{0.f,0.f,0.f,0.f}};
            #pragma unroll
            for (int kc = 0; kc < 4; ++kc)
                #pragma unroll
                for (int nt = 0; nt < 4; ++nt)
                    acc[nt] = __builtin_amdgcn_mfma_f32_16x16x32_bf16(
                        af[kc], bfrag[nt][kc], acc[nt], 0, 0, 0);

            int rb = tile * 16;
            #pragma unroll
            for (int nt = 0; nt < 4; ++nt)
                #pragma unroll
                for (int r = 0; r < 4; ++r) {
                    int row = rb + (lane >> 4) * 4 + r;
                    if (row < N)
                        h_bf[(size_t)row * CCH + nt * 16 + col] =
                            (u16)bf16_rne(acc[nt][r]);
                }

            // fused d_i/d_j epilogue: reduce 16 columns per (head, row)
            #pragma unroll
            for (int nt = 0; nt < 4; ++nt)
                #pragma unroll
                for (int r = 0; r < 4; ++r) {
                    float si = acc[nt][r] * ai_c[nt];
                    float sj = acc[nt][r] * aj_c[nt];
                    #pragma unroll
                    for (int off = 1; off < 16; off <<= 1) {
                        si += __shfl_xor(si, off);
                        sj += __shfl_xor(sj, off);
                    }
                    if (col == 0) {
                        int row = rb + (lane >> 4) * 4 + r;
                        if (row < N) {
                            d_i[row * HEADS + nt] = si;
                            d_j[row * HEADS + nt] = sj;
                        }
                    }
                }

            #pragma unroll
            for (int i = 0; i < 8; ++i) cur[i] = nxt[i];
        }
    } else {
        // ---------------- count_rank path ----------------
        int tot = E + N;
        int nquads = (tot + 3) >> 2;
        int cblocks = gridDim.x - GB;
        int cb = blockIdx.x - GB;
        for (int q = cb * 256 + t; q < nquads; q += cblocks * 256) {
            int i = q * 4;
            if (i + 3 < tot) {
                int4 cc;
                if (i + 3 < E) {
                    cc = *(const int4*)(cols + i);
                } else {
                    cc.x = (i     < E) ? cols[i]     : i - E;
                    cc.y = (i + 1 < E) ? cols[i + 1] : i + 1 - E;
                    cc.z = (i + 2 < E) ? cols[i + 2] : i + 2 - E;
                    cc.w = (i + 3 < E) ? cols[i + 3] : i + 3 - E;
                }
                int r0 = atomicAdd(&deg[cc.x], 1);
                int r1 = atomicAdd(&deg[cc.y], 1);
                int r2 = atomicAdd(&deg[cc.z], 1);
                int r3 = atomicAdd(&deg[cc.w], 1);
                *(int4*)(rank + i) = make_int4(r0, r1, r2, r3);
            } else {
                for (int e = i; e < tot; ++e) {
                    int c = (e < E) ? cols[e] : (e - E);
                    rank[e] = atomicAdd(&deg[c], 1);
                }
            }
        }
    }
}

// ---------------------------------------------------------------------------
// Scan: block-local -> add (partial prefix computed inline)
// ---------------------------------------------------------------------------
__global__ __launch_bounds__(256) void k_scan_blk(const int* __restrict__ deg,
                                                  int* __restrict__ offs,
                                                  int* __restrict__ partials, int N) {
    __shared__ int wsum[4];
    int t = threadIdx.x, lane = t & 63, wid = t >> 6;
    int base = blockIdx.x * 1024 + t * 4;
    int v0 = 0, v1 = 0, v2 = 0, v3 = 0;
    if (base + 3 < N) {
        int4 q = *(const int4*)(deg + base);
        v0 = q.x; v1 = q.y; v2 = q.z; v3 = q.w;
    } else {
        if (base     < N) v0 = deg[base];
        if (base + 1 < N) v1 = deg[base + 1];
        if (base + 2 < N) v2 = deg[base + 2];
        if (base + 3 < N) v3 = deg[base + 3];
    }
    int ts = v0 + v1 + v2 + v3;
    int sc = ts;
    #pragma unroll
    for (int off = 1; off < 64; off <<= 1) {
        int u = __shfl_up(sc, off);
        if (lane >= off) sc += u;
    }
    if (lane == 63) wsum[wid] = sc;
    __syncthreads();
    int wb = 0;
    for (int i = 0; i < wid; ++i) wb += wsum[i];
    int excl = wb + sc - ts;
    if (base     < N) offs[base]     = excl;
    if (base + 1 < N) offs[base + 1] = excl + v0;
    if (base + 2 < N) offs[base + 2] = excl + v0 + v1;
    if (base + 3 < N) offs[base + 3] = excl + v0 + v1 + v2;
    if (t == 255) partials[blockIdx.x] = wb + sc;
}

__global__ void k_scan_add(int* __restrict__ offs,
                           const int* __restrict__ partials, int N, int NB) {
    int b = blockIdx.x;
    int p = b >> 2;
    int base = 0;
    for (int j = 0; j < p; ++j) base += partials[j];
    int i = b * 256 + threadIdx.x;
    if (i < N) offs[i] += base;
    if (i == 0) {
        int tot = 0;
        for (int j = 0; j < NB; ++j) tot += partials[j];
        offs[N] = tot;
    }
}

// ---------------------------------------------------------------------------
// Scatter + alpha: pos = offs[c] + rank[e]. Record = 8 B:
//   bits [0,17): row; bits [17+11h, ...): alpha[h] as 11-bit fixed point.
// ---------------------------------------------------------------------------
__global__ __launch_bounds__(256) void k_scatter_alpha(const int* __restrict__ rows,
                                                       const int* __restrict__ cols,
                                                       const int* __restrict__ offs,
                                                       const int* __restrict__ rank,
                                                       const float* __restrict__ d_i,
                                                       const float* __restrict__ d_j,
                                                       u64* __restrict__ srec,
                                                       int E, int N) {
    int e = blockIdx.x * blockDim.x + threadIdx.x;
    if (e >= E + N) return;
    int r, c;
    if (e < E) { r = rows[e]; c = cols[e]; }
    else       { r = e - E;   c = r; }
    int pos = offs[c] + rank[e];

    float4 di4 = *(const float4*)(d_i + (size_t)r * HEADS);
    float4 dj4 = *(const float4*)(d_j + (size_t)c * HEADS);
    float l0 = di4.x + dj4.x, l1 = di4.y + dj4.y;
    float l2 = di4.z + dj4.z, l3 = di4.w + dj4.w;
    l0 = l0 > 0.f ? l0 : NEG_SLOPE * l0;
    l1 = l1 > 0.f ? l1 : NEG_SLOPE * l1;
    l2 = l2 > 0.f ? l2 : NEG_SLOPE * l2;
    l3 = l3 > 0.f ? l3 : NEG_SLOPE * l3;
    float m = fmaxf(fmaxf(l0, l1), fmaxf(l2, l3));
    float e0 = __expf(l0 - m), e1 = __expf(l1 - m);
    float e2 = __expf(l2 - m), e3 = __expf(l3 - m);
    float inv = 1.f / (e0 + e1 + e2 + e3);

    uint32 q0 = (uint32)(e0 * inv * 2047.f + 0.5f);
    uint32 q1 = (uint32)(e1 * inv * 2047.f + 0.5f);
    uint32 q2 = (uint32)(e2 * inv * 2047.f + 0.5f);
    uint32 q3 = (uint32)(e3 * inv * 2047.f + 0.5f);

    u64 rec = (u64)(uint32)r
            | ((u64)q0 << 17) | ((u64)q1 << 28)
            | ((u64)q2 << 39) | ((u64)q3 << 50);
    srec[pos] = rec;
}

// ---------------------------------------------------------------------------
// Accumulate: 4 dests per wave (16 lanes each, 4 channels/lane), unroll 8.
// ---------------------------------------------------------------------------
__global__ __launch_bounds__(256) void k_accum(const int* __restrict__ offs,
                                               const u64* __restrict__ srec,
                                               const u16* __restrict__ h_bf,
                                               const float* __restrict__ bias,
                                               float* __restrict__ out, int N) {
    int t = threadIdx.x;
    int wid = t >> 6, lane = t & 63;
    int g = lane >> 4, sub = lane & 15;
    int node = blockIdx.x * 16 + wid * 4 + g;
    int c = (node < N) ? node : N - 1;

    int s = offs[c], e = offs[c + 1];
    int deg = e - s;                       // >= 1 (self-loops)
    int md = deg;
    md = max(md, __shfl_xor(md, 16));
    md = max(md, __shfl_xor(md, 32));      // max over the wave's 4 groups

    int shift = 17 + 11 * (sub >> 2);      // this lane's head field
    float a0 = 0.f, a1 = 0.f, a2 = 0.f, a3 = 0.f;

    #pragma unroll 8
    for (int r = 0; r < md; ++r) {
        int idx = s + ((r < deg) ? r : (deg - 1));
        u64 rec = srec[idx];
        int row = (int)((uint32)rec & 0x1FFFFu);
        float a = (float)((uint32)(rec >> shift) & 0x7FFu) * (1.f / 2047.f);
        if (r >= deg) a = 0.f;
        uint2 hb = *(const uint2*)(h_bf + (size_t)row * CCH + sub * 4);
        a0 = fmaf(__uint_as_float(hb.x << 16),         a, a0);
        a1 = fmaf(__uint_as_float(hb.x & 0xffff0000u), a, a1);
        a2 = fmaf(__uint_as_float(hb.y << 16),         a, a2);
        a3 = fmaf(__uint_as_float(hb.y & 0xffff0000u), a, a3);
    }

    if (node < N) {
        float4 b = *(const float4*)(bias + sub * 4);
        float4 o = {a0 + b.x, a1 + b.y, a2 + b.z, a3 + b.w};
        *(float4*)(out + (size_t)node * CCH + sub * 4) = o;
    }
}

extern "C" void kernel_launch(void* const* d_in, const int* in_sizes, int n_in,
                              void* d_out, int out_size, void* d_ws, size_t ws_size,
                              hipStream_t stream) {
    const float* x    = (const float*)d_in[0];
    const int*   ei   = (const int*)  d_in[1];
    const float* w    = (const float*)d_in[2];
    const float* att  = (const float*)d_in[3];
    const float* bias = (const float*)d_in[4];
    float* out = (float*)d_out;

    int N = in_sizes[0] / IN_CH;
    int E = in_sizes[1] / 2;
    const int* rows = ei;
    const int* cols = ei + E;
    int total_e = E + N;
    int NB = (N + 1023) / 1024;
    int Npad = (N + 3) & ~3;

    char* ws = (char*)d_ws;
    auto carve = [&](size_t bytes) {
        char* p = ws;
        ws += (bytes + 255) & ~(size_t)255;
        return p;
    };
    u16*   h_bf   = (u16*)  carve((size_t)N * CCH * 2);          // 6.4 MB
    float* di     = (float*)carve((size_t)N * HEADS * 4);        // 0.8 MB
    float* dj     = (float*)carve((size_t)N * HEADS * 4);        // 0.8 MB
    int*   deg    = (int*)  carve((size_t)Npad * 4);
    int*   offs   = (int*)  carve((size_t)(N + 1) * 4);
    int*   parts  = (int*)  carve((size_t)(NB + 1) * 4);
    int*   rank   = (int*)  carve((size_t)total_e * 4);          // 3.4 MB
    u64*   srec   = (u64*)  carve((size_t)total_e * 8);          // 6.8 MB

    int ntiles = (N + 15) >> 4;
    int GB = (ntiles + 3) / 4;                   // gemm blocks (1 tile/wave)
    if (GB > 2048) GB = 2048;
    int gemm_waves = GB * 4;
    int CB = ((total_e + 3) / 4 + 255) / 256;    // count blocks
    if (CB > 1024) CB = 1024;

    k_zero<<<(Npad + 255) / 256, 256, 0, stream>>>(deg, Npad);
    k_fat<<<GB + CB, 256, 0, stream>>>(x, w, att, h_bf, di, dj, cols, deg, rank,
                                       N, E, GB, gemm_waves);
    k_scan_blk<<<NB, 256, 0, stream>>>(deg, offs, parts, N);
    k_scan_add<<<(N + 255) / 256, 256, 0, stream>>>(offs, parts, N, NB);
    k_scatter_alpha<<<(total_e + 255) / 256, 256, 0, stream>>>(rows, cols, offs, rank,
                                                               di, dj, srec, E, N);
    k_accum<<<(N + 15) / 16, 256, 0, stream>>>(offs, srec, h_bf, bias, out, N);
}

// Round 14
// 107.991 us; speedup vs baseline: 1.2393x; 1.0010x over previous
//
#include <hip/hip_runtime.h>

#define HEADS 4
#define OUT_CH 16
#define CCH 64            // HEADS*OUT_CH
#define IN_CH 128
#define NEG_SLOPE 0.2f

typedef unsigned int       uint32;
typedef unsigned long long u64;
typedef unsigned short     u16;
typedef __attribute__((ext_vector_type(8))) short short8;
typedef __attribute__((ext_vector_type(4))) float f32x4;

__device__ __forceinline__ uint32 bf16_rne(float f) {
    uint32 u = __float_as_uint(f);
    return (u + 0x7fffu + ((u >> 16) & 1u)) >> 16;
}

// ---------------------------------------------------------------------------
// Zero kernel
// ---------------------------------------------------------------------------
__global__ void k_zero(int* __restrict__ p, int n) {
    int i = blockIdx.x * 256 + threadIdx.x;
    if (i < n) p[i] = 0;
}

// ---------------------------------------------------------------------------
// FAT kernel: blocks [0, GB) = MFMA GEMM (+ d_i/d_j as 8 EXTRA GEMM COLUMNS,
// no shuffles); blocks [GB, ..) = count_rank (4 atomic chains/thread).
//   wX[j][k] = Σ_c W[k][h*16+c] * att[h][c (+16 for j>=4)],  h = j&3
//   => extended D cols: j<4 -> d_i[row][j], j in 4..7 -> d_j[row][j-4]
// ---------------------------------------------------------------------------
__global__ __launch_bounds__(256) void k_fat(const float* __restrict__ x,
                                             const float* __restrict__ w,
                                             const float* __restrict__ att,
                                             u16* __restrict__ h_bf,
                                             float* __restrict__ d_i,
                                             float* __restrict__ d_j,
                                             const int* __restrict__ cols,
                                             int* __restrict__ deg,
                                             int* __restrict__ rank,
                                             int N, int E, int GB, int nwaves) {
    int t = threadIdx.x;

    if ((int)blockIdx.x < GB) {
        // ---------------- GEMM path ----------------
        __shared__ u16 wT[64 * 136];   // 17.4 KB
        __shared__ u16 wX[16 * 136];   //  4.3 KB (extended att-columns)
        int lane = t & 63;

        for (int i = t; i < IN_CH * CCH; i += 256) {
            int k = i >> 6, c = i & 63;
            wT[c * 136 + k] = (u16)bf16_rne(w[i]);
        }
        // extended columns: thread t -> j = t&7, k-block = (t>>3)*4
        {
            int j = t & 7, h = j & 3;
            const float* ab = att + h * (2 * OUT_CH) + ((j >= 4) ? OUT_CH : 0);
            #pragma unroll
            for (int kk = 0; kk < 4; ++kk) {
                int k = (t >> 3) * 4 + kk;
                float s = 0.f;
                #pragma unroll
                for (int c = 0; c < 16; ++c)
                    s = fmaf(w[k * CCH + h * OUT_CH + c], ab[c], s);
                wX[j * 136 + k] = (u16)bf16_rne(s);
            }
            for (int i = t; i < 8 * 136; i += 256) wX[8 * 136 + i] = 0;
        }
        __syncthreads();

        short8 bfrag[4][4], bfrag5[4];
        int col = lane & 15;
        {
            int g = (lane >> 4) * 8;
            #pragma unroll
            for (int nt = 0; nt < 4; ++nt)
                #pragma unroll
                for (int kc = 0; kc < 4; ++kc)
                    bfrag[nt][kc] = *(const short8*)&wT[(nt * 16 + col) * 136 + kc * 32 + g];
            #pragma unroll
            for (int kc = 0; kc < 4; ++kc)
                bfrag5[kc] = *(const short8*)&wX[col * 136 + kc * 32 + g];
        }

        int gw = blockIdx.x * 4 + (t >> 6);
        int ntiles = (N + 15) >> 4;
        int row0 = lane & 15, kg = (lane >> 4) * 8;

        float4 cur[8], nxt[8];

        auto LOAD = [&](int tile, float4* buf) {
            int r = tile * 16 + row0;
            if (r >= N) r = N - 1;
            const float* xp = x + (size_t)r * IN_CH + kg;
            #pragma unroll
            for (int kc = 0; kc < 4; ++kc) {
                buf[kc * 2]     = *(const float4*)(xp + kc * 32);
                buf[kc * 2 + 1] = *(const float4*)(xp + kc * 32 + 4);
            }
        };

        int tile = gw;
        if (tile < ntiles) LOAD(tile, cur);
        for (; tile < ntiles; tile += nwaves) {
            int tn = tile + nwaves;
            if (tn < ntiles) LOAD(tn, nxt);

            short8 af[4];
            #pragma unroll
            for (int kc = 0; kc < 4; ++kc) {
                float4 u = cur[kc * 2], v = cur[kc * 2 + 1];
                short8 s;
                s[0] = (short)bf16_rne(u.x); s[1] = (short)bf16_rne(u.y);
                s[2] = (short)bf16_rne(u.z); s[3] = (short)bf16_rne(u.w);
                s[4] = (short)bf16_rne(v.x); s[5] = (short)bf16_rne(v.y);
                s[6] = (short)bf16_rne(v.z); s[7] = (short)bf16_rne(v.w);
                af[kc] = s;
            }

            f32x4 acc[4] = {{0.f,0.f,0.f,0.f},{0.f,0.f,0.f,0.f},
                            {0.f,0.f,0.f,0.f},{0.f,0.f,0.f,0.f}};
            f32x4 accX = {0.f, 0.f, 0.f, 0.f};
            #pragma unroll
            for (int kc = 0; kc < 4; ++kc) {
                #pragma unroll
                for (int nt = 0; nt < 4; ++nt)
                    acc[nt] = __builtin_amdgcn_mfma_f32_16x16x32_bf16(
                        af[kc], bfrag[nt][kc], acc[nt], 0, 0, 0);
                accX = __builtin_amdgcn_mfma_f32_16x16x32_bf16(
                    af[kc], bfrag5[kc], accX, 0, 0, 0);
            }

            int rb = tile * 16;
            #pragma unroll
            for (int nt = 0; nt < 4; ++nt)
                #pragma unroll
                for (int r = 0; r < 4; ++r) {
                    int row = rb + (lane >> 4) * 4 + r;
                    if (row < N)
                        h_bf[(size_t)row * CCH + nt * 16 + col] =
                            (u16)bf16_rne(acc[nt][r]);
                }

            if (col < 8) {
                #pragma unroll
                for (int r = 0; r < 4; ++r) {
                    int row = rb + (lane >> 4) * 4 + r;
                    if (row < N) {
                        if (col < 4) d_i[row * HEADS + col] = accX[r];
                        else         d_j[row * HEADS + (col - 4)] = accX[r];
                    }
                }
            }

            #pragma unroll
            for (int i = 0; i < 8; ++i) cur[i] = nxt[i];
        }
    } else {
        // ---------------- count_rank path ----------------
        int tot = E + N;
        int nquads = (tot + 3) >> 2;
        int cblocks = gridDim.x - GB;
        int cb = blockIdx.x - GB;
        for (int q = cb * 256 + t; q < nquads; q += cblocks * 256) {
            int i = q * 4;
            if (i + 3 < tot) {
                int4 cc;
                if (i + 3 < E) {
                    cc = *(const int4*)(cols + i);
                } else {
                    cc.x = (i     < E) ? cols[i]     : i - E;
                    cc.y = (i + 1 < E) ? cols[i + 1] : i + 1 - E;
                    cc.z = (i + 2 < E) ? cols[i + 2] : i + 2 - E;
                    cc.w = (i + 3 < E) ? cols[i + 3] : i + 3 - E;
                }
                int r0 = atomicAdd(&deg[cc.x], 1);
                int r1 = atomicAdd(&deg[cc.y], 1);
                int r2 = atomicAdd(&deg[cc.z], 1);
                int r3 = atomicAdd(&deg[cc.w], 1);
                *(int4*)(rank + i) = make_int4(r0, r1, r2, r3);
            } else {
                for (int e = i; e < tot; ++e) {
                    int c = (e < E) ? cols[e] : (e - E);
                    rank[e] = atomicAdd(&deg[c], 1);
                }
            }
        }
    }
}

// ---------------------------------------------------------------------------
// Scan: block-local -> add (partial prefix computed inline)
// ---------------------------------------------------------------------------
__global__ __launch_bounds__(256) void k_scan_blk(const int* __restrict__ deg,
                                                  int* __restrict__ offs,
                                                  int* __restrict__ partials, int N) {
    __shared__ int wsum[4];
    int t = threadIdx.x, lane = t & 63, wid = t >> 6;
    int base = blockIdx.x * 1024 + t * 4;
    int v0 = 0, v1 = 0, v2 = 0, v3 = 0;
    if (base + 3 < N) {
        int4 q = *(const int4*)(deg + base);
        v0 = q.x; v1 = q.y; v2 = q.z; v3 = q.w;
    } else {
        if (base     < N) v0 = deg[base];
        if (base + 1 < N) v1 = deg[base + 1];
        if (base + 2 < N) v2 = deg[base + 2];
        if (base + 3 < N) v3 = deg[base + 3];
    }
    int ts = v0 + v1 + v2 + v3;
    int sc = ts;
    #pragma unroll
    for (int off = 1; off < 64; off <<= 1) {
        int u = __shfl_up(sc, off);
        if (lane >= off) sc += u;
    }
    if (lane == 63) wsum[wid] = sc;
    __syncthreads();
    int wb = 0;
    for (int i = 0; i < wid; ++i) wb += wsum[i];
    int excl = wb + sc - ts;
    if (base     < N) offs[base]     = excl;
    if (base + 1 < N) offs[base + 1] = excl + v0;
    if (base + 2 < N) offs[base + 2] = excl + v0 + v1;
    if (base + 3 < N) offs[base + 3] = excl + v0 + v1 + v2;
    if (t == 255) partials[blockIdx.x] = wb + sc;
}

__global__ void k_scan_add(int* __restrict__ offs,
                           const int* __restrict__ partials, int N, int NB) {
    int b = blockIdx.x;
    int p = b >> 2;
    int base = 0;
    for (int j = 0; j < p; ++j) base += partials[j];
    int i = b * 256 + threadIdx.x;
    if (i < N) offs[i] += base;
    if (i == 0) {
        int tot = 0;
        for (int j = 0; j < NB; ++j) tot += partials[j];
        offs[N] = tot;
    }
}

// ---------------------------------------------------------------------------
// Scatter + alpha: pos = offs[c] + rank[e]. Record = 8 B:
//   bits [0,17): row; bits [17+11h, ...): alpha[h] as 11-bit fixed point.
// ---------------------------------------------------------------------------
__global__ __launch_bounds__(256) void k_scatter_alpha(const int* __restrict__ rows,
                                                       const int* __restrict__ cols,
                                                       const int* __restrict__ offs,
                                                       const int* __restrict__ rank,
                                                       const float* __restrict__ d_i,
                                                       const float* __restrict__ d_j,
                                                       u64* __restrict__ srec,
                                                       int E, int N) {
    int e = blockIdx.x * blockDim.x + threadIdx.x;
    if (e >= E + N) return;
    int r, c;
    if (e < E) { r = rows[e]; c = cols[e]; }
    else       { r = e - E;   c = r; }
    int pos = offs[c] + rank[e];

    float4 di4 = *(const float4*)(d_i + (size_t)r * HEADS);
    float4 dj4 = *(const float4*)(d_j + (size_t)c * HEADS);
    float l0 = di4.x + dj4.x, l1 = di4.y + dj4.y;
    float l2 = di4.z + dj4.z, l3 = di4.w + dj4.w;
    l0 = l0 > 0.f ? l0 : NEG_SLOPE * l0;
    l1 = l1 > 0.f ? l1 : NEG_SLOPE * l1;
    l2 = l2 > 0.f ? l2 : NEG_SLOPE * l2;
    l3 = l3 > 0.f ? l3 : NEG_SLOPE * l3;
    float m = fmaxf(fmaxf(l0, l1), fmaxf(l2, l3));
    float e0 = __expf(l0 - m), e1 = __expf(l1 - m);
    float e2 = __expf(l2 - m), e3 = __expf(l3 - m);
    float inv = 1.f / (e0 + e1 + e2 + e3);

    uint32 q0 = (uint32)(e0 * inv * 2047.f + 0.5f);
    uint32 q1 = (uint32)(e1 * inv * 2047.f + 0.5f);
    uint32 q2 = (uint32)(e2 * inv * 2047.f + 0.5f);
    uint32 q3 = (uint32)(e3 * inv * 2047.f + 0.5f);

    u64 rec = (u64)(uint32)r
            | ((u64)q0 << 17) | ((u64)q1 << 28)
            | ((u64)q2 << 39) | ((u64)q3 << 50);
    srec[pos] = rec;
}

// ---------------------------------------------------------------------------
// Accumulate: 4 dests per wave (16 lanes each, 4 channels/lane), unroll 8.
// ---------------------------------------------------------------------------
__global__ __launch_bounds__(256) void k_accum(const int* __restrict__ offs,
                                               const u64* __restrict__ srec,
                                               const u16* __restrict__ h_bf,
                                               const float* __restrict__ bias,
                                               float* __restrict__ out, int N) {
    int t = threadIdx.x;
    int wid = t >> 6, lane = t & 63;
    int g = lane >> 4, sub = lane & 15;
    int node = blockIdx.x * 16 + wid * 4 + g;
    int c = (node < N) ? node : N - 1;

    int s = offs[c], e = offs[c + 1];
    int deg = e - s;                       // >= 1 (self-loops)
    int md = deg;
    md = max(md, __shfl_xor(md, 16));
    md = max(md, __shfl_xor(md, 32));      // max over the wave's 4 groups

    int shift = 17 + 11 * (sub >> 2);      // this lane's head field
    float a0 = 0.f, a1 = 0.f, a2 = 0.f, a3 = 0.f;

    #pragma unroll 8
    for (int r = 0; r < md; ++r) {
        int idx = s + ((r < deg) ? r : (deg - 1));
        u64 rec = srec[idx];
        int row = (int)((uint32)rec & 0x1FFFFu);
        float a = (float)((uint32)(rec >> shift) & 0x7FFu) * (1.f / 2047.f);
        if (r >= deg) a = 0.f;
        uint2 hb = *(const uint2*)(h_bf + (size_t)row * CCH + sub * 4);
        a0 = fmaf(__uint_as_float(hb.x << 16),         a, a0);
        a1 = fmaf(__uint_as_float(hb.x & 0xffff0000u), a, a1);
        a2 = fmaf(__uint_as_float(hb.y << 16),         a, a2);
        a3 = fmaf(__uint_as_float(hb.y & 0xffff0000u), a, a3);
    }

    if (node < N) {
        float4 b = *(const float4*)(bias + sub * 4);
        float4 o = {a0 + b.x, a1 + b.y, a2 + b.z, a3 + b.w};
        *(float4*)(out + (size_t)node * CCH + sub * 4) = o;
    }
}

extern "C" void kernel_launch(void* const* d_in, const int* in_sizes, int n_in,
                              void* d_out, int out_size, void* d_ws, size_t ws_size,
                              hipStream_t stream) {
    const float* x    = (const float*)d_in[0];
    const int*   ei   = (const int*)  d_in[1];
    const float* w    = (const float*)d_in[2];
    const float* att  = (const float*)d_in[3];
    const float* bias = (const float*)d_in[4];
    float* out = (float*)d_out;

    int N = in_sizes[0] / IN_CH;
    int E = in_sizes[1] / 2;
    const int* rows = ei;
    const int* cols = ei + E;
    int total_e = E + N;
    int NB = (N + 1023) / 1024;
    int Npad = (N + 3) & ~3;

    char* ws = (char*)d_ws;
    auto carve = [&](size_t bytes) {
        char* p = ws;
        ws += (bytes + 255) & ~(size_t)255;
        return p;
    };
    u16*   h_bf   = (u16*)  carve((size_t)N * CCH * 2);          // 6.4 MB
    float* di     = (float*)carve((size_t)N * HEADS * 4);        // 0.8 MB
    float* dj     = (float*)carve((size_t)N * HEADS * 4);        // 0.8 MB
    int*   deg    = (int*)  carve((size_t)Npad * 4);
    int*   offs   = (int*)  carve((size_t)(N + 1) * 4);
    int*   parts  = (int*)  carve((size_t)(NB + 1) * 4);
    int*   rank   = (int*)  carve((size_t)total_e * 4);          // 3.4 MB
    u64*   srec   = (u64*)  carve((size_t)total_e * 8);          // 6.8 MB

    int ntiles = (N + 15) >> 4;
    int GB = (ntiles + 3) / 4;                   // gemm blocks (1 tile/wave)
    if (GB > 2048) GB = 2048;
    int gemm_waves = GB * 4;
    int CB = ((total_e + 3) / 4 + 255) / 256;    // count blocks
    if (CB > 1024) CB = 1024;

    k_zero<<<(Npad + 255) / 256, 256, 0, stream>>>(deg, Npad);
    k_fat<<<GB + CB, 256, 0, stream>>>(x, w, att, h_bf, di, dj, cols, deg, rank,
                                       N, E, GB, gemm_waves);
    k_scan_blk<<<NB, 256, 0, stream>>>(deg, offs, parts, N);
    k_scan_add<<<(N + 255) / 256, 256, 0, stream>>>(offs, parts, N, NB);
    k_scatter_alpha<<<(total_e + 255) / 256, 256, 0, stream>>>(rows, cols, offs, rank,
                                                               di, dj, srec, E, N);
    k_accum<<<(N + 15) / 16, 256, 0, stream>>>(offs, srec, h_bf, bias, out, N);
}

// Round 15
// 104.654 us; speedup vs baseline: 1.2788x; 1.0319x over previous
//
#include <hip/hip_runtime.h>

#define HEADS 4
#define OUT_CH 16
#define CCH 64            // HEADS*OUT_CH
#define IN_CH 128
#define NEG_SLOPE 0.2f

typedef unsigned int       uint32;
typedef unsigned long long u64;
typedef unsigned short     u16;
typedef __attribute__((ext_vector_type(8))) short short8;
typedef __attribute__((ext_vector_type(4))) float f32x4;

__device__ __forceinline__ uint32 bf16_rne(float f) {
    uint32 u = __float_as_uint(f);
    return (u + 0x7fffu + ((u >> 16) & 1u)) >> 16;
}

// ---------------------------------------------------------------------------
// Pre kernel: blocks [0, ZB) zero deg; block ZB builds the global B-side:
//   wTg[c][k] = bf16(w[k][c])                          (64 x 128, frag-contig)
//   wXg[j][k] = bf16(sum_c w[k][h*16+c]*att[h][c(+16)]) j<8, h=j&3; j>=8 -> 0
// Fragment for col c, k-slice [kc*32+g, +8) is 16 contiguous bytes.
// ---------------------------------------------------------------------------
__global__ __launch_bounds__(256) void k_pre(int* __restrict__ deg, int Npad,
                                             const float* __restrict__ w,
                                             const float* __restrict__ att,
                                             u16* __restrict__ wTg,
                                             u16* __restrict__ wXg) {
    int t = threadIdx.x;
    if ((int)blockIdx.x < (int)gridDim.x - 1) {
        int i = blockIdx.x * 256 + t;
        if (i < Npad) deg[i] = 0;
        return;
    }
    // --- prep block ---
    int c = t & 63, half = t >> 6;
    #pragma unroll
    for (int kk = 0; kk < 32; ++kk) {              // coalesced: w[k][0..63]
        int k = half * 32 + kk;
        wTg[c * 128 + k] = (u16)bf16_rne(w[k * CCH + c]);
    }
    int j = t & 7, h = j & 3, kb = t >> 3;
    const float* ab = att + h * (2 * OUT_CH) + ((j >= 4) ? OUT_CH : 0);
    #pragma unroll
    for (int kk = 0; kk < 4; ++kk) {
        int k = kb * 4 + kk;
        float s = 0.f;
        #pragma unroll
        for (int cc = 0; cc < 16; ++cc)
            s = fmaf(w[k * CCH + h * OUT_CH + cc], ab[cc], s);
        wXg[j * 128 + k] = (u16)bf16_rne(s);
    }
    for (int i = t; i < 8 * 128; i += 256) wXg[8 * 128 + i] = 0;
}

// ---------------------------------------------------------------------------
// FAT kernel: blocks [0, GB): LDS-free MFMA GEMM, wave = one 16-row tile.
//   B-frags: 20 contiguous 16 B loads from wTg/wXg (L2-hot, one-time).
//   h_bf + d_i/d_j (8 extra GEMM columns) out.
// blocks [GB, ..): count_rank, 4 atomic chains/thread, 2 quads.
// ---------------------------------------------------------------------------
__global__ __launch_bounds__(256) void k_fat(const float* __restrict__ x,
                                             const u16* __restrict__ wTg,
                                             const u16* __restrict__ wXg,
                                             u16* __restrict__ h_bf,
                                             float* __restrict__ d_i,
                                             float* __restrict__ d_j,
                                             const int* __restrict__ cols,
                                             int* __restrict__ deg,
                                             int* __restrict__ rank,
                                             int N, int E, int GB) {
    int t = threadIdx.x;

    if ((int)blockIdx.x < GB) {
        int lane = t & 63;
        int col = lane & 15, g = (lane >> 4) * 8;
        int tile = blockIdx.x * 4 + (t >> 6);
        int ntiles = (N + 15) >> 4;
        if (tile >= ntiles) return;

        // issue x loads first (longest latency)
        int r0 = tile * 16 + (lane & 15);
        if (r0 >= N) r0 = N - 1;
        const float* xp = x + (size_t)r0 * IN_CH + g;
        float4 cur[8];
        #pragma unroll
        for (int kc = 0; kc < 4; ++kc) {
            cur[kc * 2]     = *(const float4*)(xp + kc * 32);
            cur[kc * 2 + 1] = *(const float4*)(xp + kc * 32 + 4);
        }

        // B-frags from global (contiguous 16 B each, L2-broadcast)
        short8 bfrag[4][4], bfrag5[4];
        #pragma unroll
        for (int nt = 0; nt < 4; ++nt)
            #pragma unroll
            for (int kc = 0; kc < 4; ++kc)
                bfrag[nt][kc] = *(const short8*)&wTg[(nt * 16 + col) * 128 + kc * 32 + g];
        #pragma unroll
        for (int kc = 0; kc < 4; ++kc)
            bfrag5[kc] = *(const short8*)&wXg[col * 128 + kc * 32 + g];

        short8 af[4];
        #pragma unroll
        for (int kc = 0; kc < 4; ++kc) {
            float4 u = cur[kc * 2], v = cur[kc * 2 + 1];
            short8 s;
            s[0] = (short)bf16_rne(u.x); s[1] = (short)bf16_rne(u.y);
            s[2] = (short)bf16_rne(u.z); s[3] = (short)bf16_rne(u.w);
            s[4] = (short)bf16_rne(v.x); s[5] = (short)bf16_rne(v.y);
            s[6] = (short)bf16_rne(v.z); s[7] = (short)bf16_rne(v.w);
            af[kc] = s;
        }

        f32x4 acc[4] = {{0.f,0.f,0.f,0.f},{0.f,0.f,0.f,0.f},
                        {0.f,0.f,0.f,0.f},{0.f,0.f,0.f,0.f}};
        f32x4 accX = {0.f, 0.f, 0.f, 0.f};
        #pragma unroll
        for (int kc = 0; kc < 4; ++kc) {
            #pragma unroll
            for (int nt = 0; nt < 4; ++nt)
                acc[nt] = __builtin_amdgcn_mfma_f32_16x16x32_bf16(
                    af[kc], bfrag[nt][kc], acc[nt], 0, 0, 0);
            accX = __builtin_amdgcn_mfma_f32_16x16x32_bf16(
                af[kc], bfrag5[kc], accX, 0, 0, 0);
        }

        int rb = tile * 16;
        #pragma unroll
        for (int nt = 0; nt < 4; ++nt)
            #pragma unroll
            for (int r = 0; r < 4; ++r) {
                int row = rb + (lane >> 4) * 4 + r;
                if (row < N)
                    h_bf[(size_t)row * CCH + nt * 16 + col] =
                        (u16)bf16_rne(acc[nt][r]);
            }
        if (col < 8) {
            #pragma unroll
            for (int r = 0; r < 4; ++r) {
                int row = rb + (lane >> 4) * 4 + r;
                if (row < N) {
                    if (col < 4) d_i[row * HEADS + col] = accX[r];
                    else         d_j[row * HEADS + (col - 4)] = accX[r];
                }
            }
        }
    } else {
        // ---------------- count_rank path ----------------
        int tot = E + N;
        int nquads = (tot + 3) >> 2;
        int cblocks = gridDim.x - GB;
        int cb = blockIdx.x - GB;
        for (int q = cb * 256 + t; q < nquads; q += cblocks * 256) {
            int i = q * 4;
            if (i + 3 < tot) {
                int4 cc;
                if (i + 3 < E) {
                    cc = *(const int4*)(cols + i);
                } else {
                    cc.x = (i     < E) ? cols[i]     : i - E;
                    cc.y = (i + 1 < E) ? cols[i + 1] : i + 1 - E;
                    cc.z = (i + 2 < E) ? cols[i + 2] : i + 2 - E;
                    cc.w = (i + 3 < E) ? cols[i + 3] : i + 3 - E;
                }
                int r0 = atomicAdd(&deg[cc.x], 1);
                int r1 = atomicAdd(&deg[cc.y], 1);
                int r2 = atomicAdd(&deg[cc.z], 1);
                int r3 = atomicAdd(&deg[cc.w], 1);
                *(int4*)(rank + i) = make_int4(r0, r1, r2, r3);
            } else {
                for (int e = i; e < tot; ++e) {
                    int c = (e < E) ? cols[e] : (e - E);
                    rank[e] = atomicAdd(&deg[c], 1);
                }
            }
        }
    }
}

// ---------------------------------------------------------------------------
// Scan: block-local -> add (partial prefix computed inline)
// ---------------------------------------------------------------------------
__global__ __launch_bounds__(256) void k_scan_blk(const int* __restrict__ deg,
                                                  int* __restrict__ offs,
                                                  int* __restrict__ partials, int N) {
    __shared__ int wsum[4];
    int t = threadIdx.x, lane = t & 63, wid = t >> 6;
    int base = blockIdx.x * 1024 + t * 4;
    int v0 = 0, v1 = 0, v2 = 0, v3 = 0;
    if (base + 3 < N) {
        int4 q = *(const int4*)(deg + base);
        v0 = q.x; v1 = q.y; v2 = q.z; v3 = q.w;
    } else {
        if (base     < N) v0 = deg[base];
        if (base + 1 < N) v1 = deg[base + 1];
        if (base + 2 < N) v2 = deg[base + 2];
        if (base + 3 < N) v3 = deg[base + 3];
    }
    int ts = v0 + v1 + v2 + v3;
    int sc = ts;
    #pragma unroll
    for (int off = 1; off < 64; off <<= 1) {
        int u = __shfl_up(sc, off);
        if (lane >= off) sc += u;
    }
    if (lane == 63) wsum[wid] = sc;
    __syncthreads();
    int wb = 0;
    for (int i = 0; i < wid; ++i) wb += wsum[i];
    int excl = wb + sc - ts;
    if (base     < N) offs[base]     = excl;
    if (base + 1 < N) offs[base + 1] = excl + v0;
    if (base + 2 < N) offs[base + 2] = excl + v0 + v1;
    if (base + 3 < N) offs[base + 3] = excl + v0 + v1 + v2;
    if (t == 255) partials[blockIdx.x] = wb + sc;
}

__global__ void k_scan_add(int* __restrict__ offs,
                           const int* __restrict__ partials, int N, int NB) {
    int b = blockIdx.x;
    int p = b >> 2;
    int base = 0;
    for (int j = 0; j < p; ++j) base += partials[j];
    int i = b * 256 + threadIdx.x;
    if (i < N) offs[i] += base;
    if (i == 0) {
        int tot = 0;
        for (int j = 0; j < NB; ++j) tot += partials[j];
        offs[N] = tot;
    }
}

// ---------------------------------------------------------------------------
// Scatter + alpha: pos = offs[c] + rank[e]. Record = 8 B:
//   bits [0,17): row; bits [17+11h, ...): alpha[h] as 11-bit fixed point.
// ---------------------------------------------------------------------------
__global__ __launch_bounds__(256) void k_scatter_alpha(const int* __restrict__ rows,
                                                       const int* __restrict__ cols,
                                                       const int* __restrict__ offs,
                                                       const int* __restrict__ rank,
                                                       const float* __restrict__ d_i,
                                                       const float* __restrict__ d_j,
                                                       u64* __restrict__ srec,
                                                       int E, int N) {
    int e = blockIdx.x * blockDim.x + threadIdx.x;
    if (e >= E + N) return;
    int r, c;
    if (e < E) { r = rows[e]; c = cols[e]; }
    else       { r = e - E;   c = r; }
    int pos = offs[c] + rank[e];

    float4 di4 = *(const float4*)(d_i + (size_t)r * HEADS);
    float4 dj4 = *(const float4*)(d_j + (size_t)c * HEADS);
    float l0 = di4.x + dj4.x, l1 = di4.y + dj4.y;
    float l2 = di4.z + dj4.z, l3 = di4.w + dj4.w;
    l0 = l0 > 0.f ? l0 : NEG_SLOPE * l0;
    l1 = l1 > 0.f ? l1 : NEG_SLOPE * l1;
    l2 = l2 > 0.f ? l2 : NEG_SLOPE * l2;
    l3 = l3 > 0.f ? l3 : NEG_SLOPE * l3;
    float m = fmaxf(fmaxf(l0, l1), fmaxf(l2, l3));
    float e0 = __expf(l0 - m), e1 = __expf(l1 - m);
    float e2 = __expf(l2 - m), e3 = __expf(l3 - m);
    float inv = 1.f / (e0 + e1 + e2 + e3);

    uint32 q0 = (uint32)(e0 * inv * 2047.f + 0.5f);
    uint32 q1 = (uint32)(e1 * inv * 2047.f + 0.5f);
    uint32 q2 = (uint32)(e2 * inv * 2047.f + 0.5f);
    uint32 q3 = (uint32)(e3 * inv * 2047.f + 0.5f);

    u64 rec = (u64)(uint32)r
            | ((u64)q0 << 17) | ((u64)q1 << 28)
            | ((u64)q2 << 39) | ((u64)q3 << 50);
    srec[pos] = rec;
}

// ---------------------------------------------------------------------------
// Accumulate: 4 dests per wave (16 lanes each, 4 channels/lane), unroll 8.
// ---------------------------------------------------------------------------
__global__ __launch_bounds__(256) void k_accum(const int* __restrict__ offs,
                                               const u64* __restrict__ srec,
                                               const u16* __restrict__ h_bf,
                                               const float* __restrict__ bias,
                                               float* __restrict__ out, int N) {
    int t = threadIdx.x;
    int wid = t >> 6, lane = t & 63;
    int g = lane >> 4, sub = lane & 15;
    int node = blockIdx.x * 16 + wid * 4 + g;
    int c = (node < N) ? node : N - 1;

    int s = offs[c], e = offs[c + 1];
    int deg = e - s;                       // >= 1 (self-loops)
    int md = deg;
    md = max(md, __shfl_xor(md, 16));
    md = max(md, __shfl_xor(md, 32));      // max over the wave's 4 groups

    int shift = 17 + 11 * (sub >> 2);      // this lane's head field
    float a0 = 0.f, a1 = 0.f, a2 = 0.f, a3 = 0.f;

    #pragma unroll 8
    for (int r = 0; r < md; ++r) {
        int idx = s + ((r < deg) ? r : (deg - 1));
        u64 rec = srec[idx];
        int row = (int)((uint32)rec & 0x1FFFFu);
        float a = (float)((uint32)(rec >> shift) & 0x7FFu) * (1.f / 2047.f);
        if (r >= deg) a = 0.f;
        uint2 hb = *(const uint2*)(h_bf + (size_t)row * CCH + sub * 4);
        a0 = fmaf(__uint_as_float(hb.x << 16),         a, a0);
        a1 = fmaf(__uint_as_float(hb.x & 0xffff0000u), a, a1);
        a2 = fmaf(__uint_as_float(hb.y << 16),         a, a2);
        a3 = fmaf(__uint_as_float(hb.y & 0xffff0000u), a, a3);
    }

    if (node < N) {
        float4 b = *(const float4*)(bias + sub * 4);
        float4 o = {a0 + b.x, a1 + b.y, a2 + b.z, a3 + b.w};
        *(float4*)(out + (size_t)node * CCH + sub * 4) = o;
    }
}

extern "C" void kernel_launch(void* const* d_in, const int* in_sizes, int n_in,
                              void* d_out, int out_size, void* d_ws, size_t ws_size,
                              hipStream_t stream) {
    const float* x    = (const float*)d_in[0];
    const int*   ei   = (const int*)  d_in[1];
    const float* w    = (const float*)d_in[2];
    const float* att  = (const float*)d_in[3];
    const float* bias = (const float*)d_in[4];
    float* out = (float*)d_out;

    int N = in_sizes[0] / IN_CH;
    int E = in_sizes[1] / 2;
    const int* rows = ei;
    const int* cols = ei + E;
    int total_e = E + N;
    int NB = (N + 1023) / 1024;
    int Npad = (N + 3) & ~3;

    char* ws = (char*)d_ws;
    auto carve = [&](size_t bytes) {
        char* p = ws;
        ws += (bytes + 255) & ~(size_t)255;
        return p;
    };
    u16*   h_bf   = (u16*)  carve((size_t)N * CCH * 2);          // 6.4 MB
    float* di     = (float*)carve((size_t)N * HEADS * 4);        // 0.8 MB
    float* dj     = (float*)carve((size_t)N * HEADS * 4);        // 0.8 MB
    int*   deg    = (int*)  carve((size_t)Npad * 4);
    int*   offs   = (int*)  carve((size_t)(N + 1) * 4);
    int*   parts  = (int*)  carve((size_t)(NB + 1) * 4);
    int*   rank   = (int*)  carve((size_t)total_e * 4);          // 3.4 MB
    u64*   srec   = (u64*)  carve((size_t)total_e * 8);          // 6.8 MB
    u16*   wTg    = (u16*)  carve((size_t)64 * 128 * 2);         // 16 KB
    u16*   wXg    = (u16*)  carve((size_t)16 * 128 * 2);         // 4 KB

    int ntiles = (N + 15) >> 4;
    int GB = (ntiles + 3) / 4;                   // gemm blocks: 1 tile/wave
    int CB = ((total_e + 3) / 4 + 511) / 512;    // count blocks: 2 quads/thread
    int ZB = (Npad + 255) / 256;

    k_pre<<<ZB + 1, 256, 0, stream>>>(deg, Npad, w, att, wTg, wXg);
    k_fat<<<GB + CB, 256, 0, stream>>>(x, wTg, wXg, h_bf, di, dj, cols, deg, rank,
                                       N, E, GB);
    k_scan_blk<<<NB, 256, 0, stream>>>(deg, offs, parts, N);
    k_scan_add<<<(N + 255) / 256, 256, 0, stream>>>(offs, parts, N, NB);
    k_scatter_alpha<<<(total_e + 255) / 256, 256, 0, stream>>>(rows, cols, offs, rank,
                                                               di, dj, srec, E, N);
    k_accum<<<(N + 15) / 16, 256, 0, stream>>>(offs, srec, h_bf, bias, out, N);
}

// Round 16
// 103.144 us; speedup vs baseline: 1.2976x; 1.0146x over previous
//
#include <hip/hip_runtime.h>

#define HEADS 4
#define OUT_CH 16
#define CCH 64            // HEADS*OUT_CH
#define IN_CH 128
#define NEG_SLOPE 0.2f

typedef unsigned int       uint32;
typedef unsigned long long u64;
typedef unsigned short     u16;
typedef __attribute__((ext_vector_type(8))) short short8;
typedef __attribute__((ext_vector_type(4))) float f32x4;

__device__ __forceinline__ uint32 bf16_rne(float f) {
    uint32 u = __float_as_uint(f);
    return (u + 0x7fffu + ((u >> 16) & 1u)) >> 16;
}

// ---------------------------------------------------------------------------
// Pre kernel: blocks [0, ZB) zero deg; block ZB builds the global B-side:
//   wTg[c][k] = bf16(w[k][c])                          (64 x 128, frag-contig)
//   wXg[j][k] = bf16(sum_c w[k][h*16+c]*att[h][c(+16)]) j<8, h=j&3; j>=8 -> 0
// ---------------------------------------------------------------------------
__global__ __launch_bounds__(256) void k_pre(int* __restrict__ deg, int Npad,
                                             const float* __restrict__ w,
                                             const float* __restrict__ att,
                                             u16* __restrict__ wTg,
                                             u16* __restrict__ wXg) {
    int t = threadIdx.x;
    if ((int)blockIdx.x < (int)gridDim.x - 1) {
        int i = blockIdx.x * 256 + t;
        if (i < Npad) deg[i] = 0;
        return;
    }
    int c = t & 63, half = t >> 6;
    #pragma unroll
    for (int kk = 0; kk < 32; ++kk) {
        int k = half * 32 + kk;
        wTg[c * 128 + k] = (u16)bf16_rne(w[k * CCH + c]);
    }
    int j = t & 7, h = j & 3, kb = t >> 3;
    const float* ab = att + h * (2 * OUT_CH) + ((j >= 4) ? OUT_CH : 0);
    #pragma unroll
    for (int kk = 0; kk < 4; ++kk) {
        int k = kb * 4 + kk;
        float s = 0.f;
        #pragma unroll
        for (int cc = 0; cc < 16; ++cc)
            s = fmaf(w[k * CCH + h * OUT_CH + cc], ab[cc], s);
        wXg[j * 128 + k] = (u16)bf16_rne(s);
    }
    for (int i = t; i < 8 * 128; i += 256) wXg[8 * 128 + i] = 0;
}

// ---------------------------------------------------------------------------
// FAT kernel: blocks [0, GB): LDS-free MFMA GEMM, wave = one 16-row tile.
// blocks [GB, ..): count_rank, ONE quad per thread (max atomic MLP).
// ---------------------------------------------------------------------------
__global__ __launch_bounds__(256) void k_fat(const float* __restrict__ x,
                                             const u16* __restrict__ wTg,
                                             const u16* __restrict__ wXg,
                                             u16* __restrict__ h_bf,
                                             float* __restrict__ d_i,
                                             float* __restrict__ d_j,
                                             const int* __restrict__ cols,
                                             int* __restrict__ deg,
                                             int* __restrict__ rank,
                                             int N, int E, int GB) {
    int t = threadIdx.x;

    if ((int)blockIdx.x < GB) {
        int lane = t & 63;
        int col = lane & 15, g = (lane >> 4) * 8;
        int tile = blockIdx.x * 4 + (t >> 6);
        int ntiles = (N + 15) >> 4;
        if (tile >= ntiles) return;

        // issue x loads first (longest latency)
        int r0 = tile * 16 + (lane & 15);
        if (r0 >= N) r0 = N - 1;
        const float* xp = x + (size_t)r0 * IN_CH + g;
        float4 cur[8];
        #pragma unroll
        for (int kc = 0; kc < 4; ++kc) {
            cur[kc * 2]     = *(const float4*)(xp + kc * 32);
            cur[kc * 2 + 1] = *(const float4*)(xp + kc * 32 + 4);
        }

        short8 bfrag[4][4], bfrag5[4];
        #pragma unroll
        for (int nt = 0; nt < 4; ++nt)
            #pragma unroll
            for (int kc = 0; kc < 4; ++kc)
                bfrag[nt][kc] = *(const short8*)&wTg[(nt * 16 + col) * 128 + kc * 32 + g];
        #pragma unroll
        for (int kc = 0; kc < 4; ++kc)
            bfrag5[kc] = *(const short8*)&wXg[col * 128 + kc * 32 + g];

        short8 af[4];
        #pragma unroll
        for (int kc = 0; kc < 4; ++kc) {
            float4 u = cur[kc * 2], v = cur[kc * 2 + 1];
            short8 s;
            s[0] = (short)bf16_rne(u.x); s[1] = (short)bf16_rne(u.y);
            s[2] = (short)bf16_rne(u.z); s[3] = (short)bf16_rne(u.w);
            s[4] = (short)bf16_rne(v.x); s[5] = (short)bf16_rne(v.y);
            s[6] = (short)bf16_rne(v.z); s[7] = (short)bf16_rne(v.w);
            af[kc] = s;
        }

        f32x4 acc[4] = {{0.f,0.f,0.f,0.f},{0.f,0.f,0.f,0.f},
                        {0.f,0.f,0.f,0.f},{0.f,0.f,0.f,0.f}};
        f32x4 accX = {0.f, 0.f, 0.f, 0.f};
        #pragma unroll
        for (int kc = 0; kc < 4; ++kc) {
            #pragma unroll
            for (int nt = 0; nt < 4; ++nt)
                acc[nt] = __builtin_amdgcn_mfma_f32_16x16x32_bf16(
                    af[kc], bfrag[nt][kc], acc[nt], 0, 0, 0);
            accX = __builtin_amdgcn_mfma_f32_16x16x32_bf16(
                af[kc], bfrag5[kc], accX, 0, 0, 0);
        }

        int rb = tile * 16;
        #pragma unroll
        for (int nt = 0; nt < 4; ++nt)
            #pragma unroll
            for (int r = 0; r < 4; ++r) {
                int row = rb + (lane >> 4) * 4 + r;
                if (row < N)
                    h_bf[(size_t)row * CCH + nt * 16 + col] =
                        (u16)bf16_rne(acc[nt][r]);
            }
        if (col < 8) {
            #pragma unroll
            for (int r = 0; r < 4; ++r) {
                int row = rb + (lane >> 4) * 4 + r;
                if (row < N) {
                    if (col < 4) d_i[row * HEADS + col] = accX[r];
                    else         d_j[row * HEADS + (col - 4)] = accX[r];
                }
            }
        }
    } else {
        // ---------------- count_rank path: 1 quad/thread ----------------
        int tot = E + N;
        int i = (((int)blockIdx.x - GB) * 256 + t) * 4;
        if (i + 3 < tot) {
            int4 cc;
            if (i + 3 < E) {
                cc = *(const int4*)(cols + i);
            } else {
                cc.x = (i     < E) ? cols[i]     : i - E;
                cc.y = (i + 1 < E) ? cols[i + 1] : i + 1 - E;
                cc.z = (i + 2 < E) ? cols[i + 2] : i + 2 - E;
                cc.w = (i + 3 < E) ? cols[i + 3] : i + 3 - E;
            }
            int r0 = atomicAdd(&deg[cc.x], 1);
            int r1 = atomicAdd(&deg[cc.y], 1);
            int r2 = atomicAdd(&deg[cc.z], 1);
            int r3 = atomicAdd(&deg[cc.w], 1);
            *(int4*)(rank + i) = make_int4(r0, r1, r2, r3);
        } else {
            for (int e = i; e < tot; ++e) {
                int c = (e < E) ? cols[e] : (e - E);
                rank[e] = atomicAdd(&deg[c], 1);
            }
        }
    }
}

// ---------------------------------------------------------------------------
// Scan: block-local -> add (partial prefix computed inline)
// ---------------------------------------------------------------------------
__global__ __launch_bounds__(256) void k_scan_blk(const int* __restrict__ deg,
                                                  int* __restrict__ offs,
                                                  int* __restrict__ partials, int N) {
    __shared__ int wsum[4];
    int t = threadIdx.x, lane = t & 63, wid = t >> 6;
    int base = blockIdx.x * 1024 + t * 4;
    int v0 = 0, v1 = 0, v2 = 0, v3 = 0;
    if (base + 3 < N) {
        int4 q = *(const int4*)(deg + base);
        v0 = q.x; v1 = q.y; v2 = q.z; v3 = q.w;
    } else {
        if (base     < N) v0 = deg[base];
        if (base + 1 < N) v1 = deg[base + 1];
        if (base + 2 < N) v2 = deg[base + 2];
        if (base + 3 < N) v3 = deg[base + 3];
    }
    int ts = v0 + v1 + v2 + v3;
    int sc = ts;
    #pragma unroll
    for (int off = 1; off < 64; off <<= 1) {
        int u = __shfl_up(sc, off);
        if (lane >= off) sc += u;
    }
    if (lane == 63) wsum[wid] = sc;
    __syncthreads();
    int wb = 0;
    for (int i = 0; i < wid; ++i) wb += wsum[i];
    int excl = wb + sc - ts;
    if (base     < N) offs[base]     = excl;
    if (base + 1 < N) offs[base + 1] = excl + v0;
    if (base + 2 < N) offs[base + 2] = excl + v0 + v1;
    if (base + 3 < N) offs[base + 3] = excl + v0 + v1 + v2;
    if (t == 255) partials[blockIdx.x] = wb + sc;
}

__global__ void k_scan_add(int* __restrict__ offs,
                           const int* __restrict__ partials, int N, int NB) {
    int b = blockIdx.x;
    int p = b >> 2;
    int base = 0;
    for (int j = 0; j < p; ++j) base += partials[j];
    int i = b * 256 + threadIdx.x;
    if (i < N) offs[i] += base;
    if (i == 0) {
        int tot = 0;
        for (int j = 0; j < NB; ++j) tot += partials[j];
        offs[N] = tot;
    }
}

// ---------------------------------------------------------------------------
// Scatter + alpha: pos = offs[c] + rank[e]. Record = 8 B:
//   bits [0,17): row; bits [17+11h, ...): alpha[h] as 11-bit fixed point.
// ---------------------------------------------------------------------------
__global__ __launch_bounds__(256) void k_scatter_alpha(const int* __restrict__ rows,
                                                       const int* __restrict__ cols,
                                                       const int* __restrict__ offs,
                                                       const int* __restrict__ rank,
                                                       const float* __restrict__ d_i,
                                                       const float* __restrict__ d_j,
                                                       u64* __restrict__ srec,
                                                       int E, int N) {
    int e = blockIdx.x * blockDim.x + threadIdx.x;
    if (e >= E + N) return;
    int r, c;
    if (e < E) { r = rows[e]; c = cols[e]; }
    else       { r = e - E;   c = r; }
    int pos = offs[c] + rank[e];

    float4 di4 = *(const float4*)(d_i + (size_t)r * HEADS);
    float4 dj4 = *(const float4*)(d_j + (size_t)c * HEADS);
    float l0 = di4.x + dj4.x, l1 = di4.y + dj4.y;
    float l2 = di4.z + dj4.z, l3 = di4.w + dj4.w;
    l0 = l0 > 0.f ? l0 : NEG_SLOPE * l0;
    l1 = l1 > 0.f ? l1 : NEG_SLOPE * l1;
    l2 = l2 > 0.f ? l2 : NEG_SLOPE * l2;
    l3 = l3 > 0.f ? l3 : NEG_SLOPE * l3;
    float m = fmaxf(fmaxf(l0, l1), fmaxf(l2, l3));
    float e0 = __expf(l0 - m), e1 = __expf(l1 - m);
    float e2 = __expf(l2 - m), e3 = __expf(l3 - m);
    float inv = 1.f / (e0 + e1 + e2 + e3);

    uint32 q0 = (uint32)(e0 * inv * 2047.f + 0.5f);
    uint32 q1 = (uint32)(e1 * inv * 2047.f + 0.5f);
    uint32 q2 = (uint32)(e2 * inv * 2047.f + 0.5f);
    uint32 q3 = (uint32)(e3 * inv * 2047.f + 0.5f);

    u64 rec = (u64)(uint32)r
            | ((u64)q0 << 17) | ((u64)q1 << 28)
            | ((u64)q2 << 39) | ((u64)q3 << 50);
    srec[pos] = rec;
}

// ---------------------------------------------------------------------------
// Accumulate: 4 dests per wave (16 lanes each, 4 channels/lane), unroll 8.
// ---------------------------------------------------------------------------
__global__ __launch_bounds__(256) void k_accum(const int* __restrict__ offs,
                                               const u64* __restrict__ srec,
                                               const u16* __restrict__ h_bf,
                                               const float* __restrict__ bias,
                                               float* __restrict__ out, int N) {
    int t = threadIdx.x;
    int wid = t >> 6, lane = t & 63;
    int g = lane >> 4, sub = lane & 15;
    int node = blockIdx.x * 16 + wid * 4 + g;
    int c = (node < N) ? node : N - 1;

    int s = offs[c], e = offs[c + 1];
    int deg = e - s;                       // >= 1 (self-loops)
    int md = deg;
    md = max(md, __shfl_xor(md, 16));
    md = max(md, __shfl_xor(md, 32));      // max over the wave's 4 groups

    int shift = 17 + 11 * (sub >> 2);      // this lane's head field
    float a0 = 0.f, a1 = 0.f, a2 = 0.f, a3 = 0.f;

    #pragma unroll 8
    for (int r = 0; r < md; ++r) {
        int idx = s + ((r < deg) ? r : (deg - 1));
        u64 rec = srec[idx];
        int row = (int)((uint32)rec & 0x1FFFFu);
        float a = (float)((uint32)(rec >> shift) & 0x7FFu) * (1.f / 2047.f);
        if (r >= deg) a = 0.f;
        uint2 hb = *(const uint2*)(h_bf + (size_t)row * CCH + sub * 4);
        a0 = fmaf(__uint_as_float(hb.x << 16),         a, a0);
        a1 = fmaf(__uint_as_float(hb.x & 0xffff0000u), a, a1);
        a2 = fmaf(__uint_as_float(hb.y << 16),         a, a2);
        a3 = fmaf(__uint_as_float(hb.y & 0xffff0000u), a, a3);
    }

    if (node < N) {
        float4 b = *(const float4*)(bias + sub * 4);
        float4 o = {a0 + b.x, a1 + b.y, a2 + b.z, a3 + b.w};
        *(float4*)(out + (size_t)node * CCH + sub * 4) = o;
    }
}

extern "C" void kernel_launch(void* const* d_in, const int* in_sizes, int n_in,
                              void* d_out, int out_size, void* d_ws, size_t ws_size,
                              hipStream_t stream) {
    const float* x    = (const float*)d_in[0];
    const int*   ei   = (const int*)  d_in[1];
    const float* w    = (const float*)d_in[2];
    const float* att  = (const float*)d_in[3];
    const float* bias = (const float*)d_in[4];
    float* out = (float*)d_out;

    int N = in_sizes[0] / IN_CH;
    int E = in_sizes[1] / 2;
    const int* rows = ei;
    const int* cols = ei + E;
    int total_e = E + N;
    int NB = (N + 1023) / 1024;
    int Npad = (N + 3) & ~3;

    char* ws = (char*)d_ws;
    auto carve = [&](size_t bytes) {
        char* p = ws;
        ws += (bytes + 255) & ~(size_t)255;
        return p;
    };
    u16*   h_bf   = (u16*)  carve((size_t)N * CCH * 2);          // 6.4 MB
    float* di     = (float*)carve((size_t)N * HEADS * 4);        // 0.8 MB
    float* dj     = (float*)carve((size_t)N * HEADS * 4);        // 0.8 MB
    int*   deg    = (int*)  carve((size_t)Npad * 4);
    int*   offs   = (int*)  carve((size_t)(N + 1) * 4);
    int*   parts  = (int*)  carve((size_t)(NB + 1) * 4);
    int*   rank   = (int*)  carve((size_t)total_e * 4);          // 3.4 MB
    u64*   srec   = (u64*)  carve((size_t)total_e * 8);          // 6.8 MB
    u16*   wTg    = (u16*)  carve((size_t)64 * 128 * 2);         // 16 KB
    u16*   wXg    = (u16*)  carve((size_t)16 * 128 * 2);         // 4 KB

    int ntiles = (N + 15) >> 4;
    int GB = (ntiles + 3) / 4;                   // gemm blocks: 1 tile/wave
    int CB = ((total_e + 3) / 4 + 255) / 256;    // count blocks: 1 quad/thread
    int ZB = (Npad + 255) / 256;

    k_pre<<<ZB + 1, 256, 0, stream>>>(deg, Npad, w, att, wTg, wXg);
    k_fat<<<GB + CB, 256, 0, stream>>>(x, wTg, wXg, h_bf, di, dj, cols, deg, rank,
                                       N, E, GB);
    k_scan_blk<<<NB, 256, 0, stream>>>(deg, offs, parts, N);
    k_scan_add<<<(N + 255) / 256, 256, 0, stream>>>(offs, parts, N, NB);
    k_scatter_alpha<<<(total_e + 255) / 256, 256, 0, stream>>>(rows, cols, offs, rank,
                                                               di, dj, srec, E, N);
    k_accum<<<(N + 15) / 16, 256, 0, stream>>>(offs, srec, h_bf, bias, out, N);
}